// Round 2
// baseline (493.825 us; speedup 1.0000x reference)
//
#include <hip/hip_runtime.h>
#include <hip/hip_bf16.h>

#define HW 3136
#define HH 56
#define WW 56
#define BB 4
#define CC 256
#define HD 128

__device__ __forceinline__ float waveRed(float v) {
#pragma unroll
    for (int m = 32; m > 0; m >>= 1) v += __shfl_xor(v, m, 64);
    return v;
}

// ---------------- K1: q/k/v 1x1 conv (GEMM), out layout [b][pixel][o] fp32 ----
__global__ __launch_bounds__(256) void qkv_gemm(
    const float* __restrict__ x,
    const float* __restrict__ Wq,
    const float* __restrict__ Wk,
    const float* __restrict__ Wv,
    float* __restrict__ q_ws, float* __restrict__ k_ws, float* __restrict__ v_ws)
{
    int wsel = blockIdx.z >> 2;      // 0:q 1:k 2:v
    int b = blockIdx.z & 3;
    const float* Wm = (wsel == 0) ? Wq : ((wsel == 1) ? Wk : Wv);
    float* outp = (wsel == 0) ? q_ws : ((wsel == 1) ? k_ws : v_ws);
    int p0 = blockIdx.x * 64, o0 = blockIdx.y * 64;

    __shared__ float As[16][68];
    __shared__ float Bs[16][68];
    int t = threadIdx.x;
    int o4 = (t & 15) * 4, p4g = (t >> 4) * 4;
    float acc[4][4] = {};
    const float* xb = x + (size_t)b * CC * HW;

    for (int c0 = 0; c0 < 256; c0 += 16) {
        {   // A tile: As[kk][p] = x[b][c0+kk][p0+p]
            int kk = t >> 4, pp = (t & 15) * 4;
            float4 f = *(const float4*)(xb + (size_t)(c0 + kk) * HW + p0 + pp);
            *(float4*)&As[kk][pp] = f;
        }
        {   // B tile: Bs[kk][o] = W[o0+o][c0+kk]
            int oo = t >> 2, k4 = (t & 3) * 4;
            float4 u = *(const float4*)(Wm + (size_t)(o0 + oo) * 256 + c0 + k4);
            Bs[k4 + 0][oo] = u.x; Bs[k4 + 1][oo] = u.y;
            Bs[k4 + 2][oo] = u.z; Bs[k4 + 3][oo] = u.w;
        }
        __syncthreads();
#pragma unroll
        for (int kk = 0; kk < 16; kk++) {
            float4 a4 = *(float4*)&As[kk][p4g];
            float4 b4 = *(float4*)&Bs[kk][o4];
            float a[4] = {a4.x, a4.y, a4.z, a4.w};
            float bb[4] = {b4.x, b4.y, b4.z, b4.w};
#pragma unroll
            for (int i = 0; i < 4; i++)
#pragma unroll
                for (int j = 0; j < 4; j++) acc[i][j] += a[i] * bb[j];
        }
        __syncthreads();
    }
    float* ob = outp + (size_t)b * HW * CC;
#pragma unroll
    for (int i = 0; i < 4; i++) {
        float4 r = make_float4(acc[i][0], acc[i][1], acc[i][2], acc[i][3]);
        *(float4*)(ob + (size_t)(p0 + p4g + i) * CC + o0 + o4) = r;
    }
}

// ---------------- K2: local attention, wave per (b, head, pixel) -------------
__global__ __launch_bounds__(256) void attn_kernel(
    const float* __restrict__ q_ws, const float* __restrict__ k_ws,
    const float* __restrict__ v_ws,
    const float* __restrict__ rel_h, const float* __restrict__ rel_w,
    float* __restrict__ ao_ws)
{
    int wid = blockIdx.x * 4 + (threadIdx.x >> 6);   // 0..50175
    int lane = threadIdx.x & 63;
    int b = wid / (2 * HW);
    int r = wid - b * (2 * HW);
    int n = r / HW;
    int hw = r - n * HW;
    int h = hw / WW, w = hw - h * WW;

    const float* qp = q_ws + ((size_t)(b * HW + hw) * CC + n * HD);
    float2 qv = *(const float2*)(qp + 2 * lane);

    const float* rel = (n == 0) ? rel_h : rel_w;
    float qb[5];
#pragma unroll
    for (int tt = 0; tt < 5; tt++) {
        float p = qv.x * rel[(2 * lane) * 5 + tt] +
                  qv.y * rel[(2 * lane + 1) * 5 + tt];
        qb[tt] = waveRed(p);
    }
    const float inv = 0.08838834764831845f;  // 1/sqrt(128)
    float s[25];
    float mx = -1e30f;
#pragma unroll
    for (int di = 0; di < 5; di++) {
        int hh = h + di - 2;
#pragma unroll
        for (int dj = 0; dj < 5; dj++) {
            int ww = w + dj - 2;
            int tt = di * 5 + dj;
            float dot = 0.f;
            if (hh >= 0 && hh < HH && ww >= 0 && ww < WW) {
                float2 kv = *(const float2*)(k_ws +
                    ((size_t)(b * HW + hh * WW + ww) * CC + n * HD) + 2 * lane);
                dot = waveRed(qv.x * kv.x + qv.y * kv.y);
            }
            float bias = (n == 0) ? qb[di] : qb[dj];
            s[tt] = (dot + bias) * inv;
            mx = fmaxf(mx, s[tt]);
        }
    }
    float sum = 0.f;
#pragma unroll
    for (int tt = 0; tt < 25; tt++) { s[tt] = __expf(s[tt] - mx); sum += s[tt]; }
    float rs = 1.f / sum;
    float2 acc = make_float2(0.f, 0.f);
#pragma unroll
    for (int di = 0; di < 5; di++) {
        int hh = h + di - 2;
#pragma unroll
        for (int dj = 0; dj < 5; dj++) {
            int ww = w + dj - 2;
            if (hh >= 0 && hh < HH && ww >= 0 && ww < WW) {
                float2 v2 = *(const float2*)(v_ws +
                    ((size_t)(b * HW + hh * WW + ww) * CC + n * HD) + 2 * lane);
                float a = s[di * 5 + dj] * rs;
                acc.x += a * v2.x; acc.y += a * v2.y;
            }
        }
    }
    *(float2*)(ao_ws + ((size_t)(b * HW + hw) * CC + n * HD) + 2 * lane) = acc;
}

// ---------------- K3: BN1+ReLU -> agg GEMM -> BN2, [b][p][o] fp32 ------------
__global__ __launch_bounds__(256) void agg_gemm(
    const float* __restrict__ ao, const float* __restrict__ aggW,
    const float* __restrict__ g1, const float* __restrict__ b1,
    const float* __restrict__ m1, const float* __restrict__ v1,
    const float* __restrict__ g2, const float* __restrict__ b2,
    const float* __restrict__ m2, const float* __restrict__ v2,
    float* __restrict__ y2)
{
    int b = blockIdx.z;
    int p0 = blockIdx.x * 64, o0 = blockIdx.y * 64;
    __shared__ float As[16][68];
    __shared__ float Bs[16][68];
    int t = threadIdx.x;
    int o4 = (t & 15) * 4, p4g = (t >> 4) * 4;
    float acc[4][4] = {};
    const float* aob = ao + (size_t)b * HW * CC;

    for (int c0 = 0; c0 < 256; c0 += 16) {
        {   // A tile with fused BN1+ReLU, transposed store
            int p = t >> 2, k4 = (t & 3) * 4;
            float4 a = *(const float4*)(aob + (size_t)(p0 + p) * CC + c0 + k4);
            float av[4] = {a.x, a.y, a.z, a.w};
#pragma unroll
            for (int u = 0; u < 4; u++) {
                int c = c0 + k4 + u;
                float sc = g1[c] * rsqrtf(v1[c] + 1e-5f);
                float val = (av[u] - m1[c]) * sc + b1[c];
                As[k4 + u][p] = fmaxf(val, 0.f);
            }
        }
        {
            int oo = t >> 2, k4 = (t & 3) * 4;
            float4 u = *(const float4*)(aggW + (size_t)(o0 + oo) * 256 + c0 + k4);
            Bs[k4 + 0][oo] = u.x; Bs[k4 + 1][oo] = u.y;
            Bs[k4 + 2][oo] = u.z; Bs[k4 + 3][oo] = u.w;
        }
        __syncthreads();
#pragma unroll
        for (int kk = 0; kk < 16; kk++) {
            float4 a4 = *(float4*)&As[kk][p4g];
            float4 b4 = *(float4*)&Bs[kk][o4];
            float a[4] = {a4.x, a4.y, a4.z, a4.w};
            float bb[4] = {b4.x, b4.y, b4.z, b4.w};
#pragma unroll
            for (int i = 0; i < 4; i++)
#pragma unroll
                for (int j = 0; j < 4; j++) acc[i][j] += a[i] * bb[j];
        }
        __syncthreads();
    }
    float* yb = y2 + (size_t)b * HW * CC;
#pragma unroll
    for (int i = 0; i < 4; i++) {
        float r[4];
#pragma unroll
        for (int j = 0; j < 4; j++) {
            int o = o0 + o4 + j;
            float sc = g2[o] * rsqrtf(v2[o] + 1e-5f);
            r[j] = (acc[i][j] - m2[o]) * sc + b2[o];
        }
        *(float4*)(yb + (size_t)(p0 + p4g + i) * CC + o0 + o4) =
            make_float4(r[0], r[1], r[2], r[3]);
    }
}

// ---------------- K4: SE squeeze conv + partial mean -------------------------
__global__ __launch_bounds__(256) void se_in_kernel(
    const float* __restrict__ y2, const float* __restrict__ se_Win,
    const float* __restrict__ gin, const float* __restrict__ bin,
    const float* __restrict__ min_, const float* __restrict__ vin,
    float* __restrict__ s_ws, float* __restrict__ psum)
{
    int b = blockIdx.y;
    int p0 = blockIdx.x * 16;
    __shared__ float yt[16][257];
    __shared__ float wt[16][257];
    __shared__ float red[16][17];
    int t = threadIdx.x;
    const float* yb = y2 + (size_t)(b * HW + p0) * CC;
#pragma unroll
    for (int i = 0; i < 16; i++) yt[i][t] = yb[(size_t)i * CC + t];
#pragma unroll
    for (int i = 0; i < 16; i++) wt[i][t] = se_Win[i * 256 + t];
    __syncthreads();
    int p = t >> 4, j = t & 15;
    float dot = 0.f;
#pragma unroll 8
    for (int c = 0; c < 256; c++) dot += yt[p][c] * wt[j][c];
    float sc = gin[j] * rsqrtf(vin[j] + 1e-5f);
    float sv = fmaxf((dot - min_[j]) * sc + bin[j], 0.f);
    s_ws[(size_t)(b * HW + p0 + p) * 16 + j] = sv;
    red[p][j] = sv;
    __syncthreads();
    if (t < 16) {
        float sm = 0.f;
#pragma unroll
        for (int pp = 0; pp < 16; pp++) sm += red[pp][t];
        atomicAdd(&psum[b * 16 + t], sm);
    }
}

__global__ void zero64(float* p) { p[threadIdx.x] = 0.f; }

// ---------------- K5: SE gate ------------------------------------------------
__global__ void se_gate(const float* __restrict__ psum,
                        const float* __restrict__ fc1,
                        const float* __restrict__ fc2,
                        float* __restrict__ g_ws)
{
    int t = threadIdx.x;
    if (t >= 64) return;
    int b = t >> 4, j = t & 15;
    float h = 0.f;
#pragma unroll
    for (int jj = 0; jj < 16; jj++)
        h += (psum[b * 16 + jj] * (1.f / 3136.f)) * fc1[jj];
    h = fmaxf(h, 0.f);
    float z = h * fc2[j];
    g_ws[t] = 1.f / (1.f + __expf(-z));
}

// ---------------- K6: SE excite conv + BN + fp32 store (NCHW) ----------------
__global__ __launch_bounds__(256) void se_out_kernel(
    const float* __restrict__ s_ws, const float* __restrict__ g_ws,
    const float* __restrict__ se_Wout,
    const float* __restrict__ gout, const float* __restrict__ bout,
    const float* __restrict__ mout, const float* __restrict__ vout,
    float* __restrict__ out)
{
    int b = blockIdx.z;
    int o0 = blockIdx.y * 4;
    int p0 = blockIdx.x * 64;
    __shared__ float st[64][17];
    __shared__ float wg[4][16];
    int t = threadIdx.x;
#pragma unroll
    for (int i = 0; i < 4; i++) {
        int idx = i * 256 + t;
        st[idx >> 4][idx & 15] = s_ws[(size_t)(b * HW + p0 + (idx >> 4)) * 16 + (idx & 15)];
    }
    if (t < 64) {
        int ol = t >> 4, j = t & 15;
        wg[ol][j] = se_Wout[(o0 + ol) * 16 + j] * g_ws[b * 16 + j];
    }
    __syncthreads();
    int ol = t >> 6, pl = t & 63;
    float dot = 0.f;
#pragma unroll
    for (int j = 0; j < 16; j++) dot += st[pl][j] * wg[ol][j];
    int o = o0 + ol;
    float sc = gout[o] * rsqrtf(vout[o] + 1e-5f);
    float r = (dot - mout[o]) * sc + bout[o];
    out[((size_t)(b * 256 + o)) * HW + p0 + pl] = r;
}

extern "C" void kernel_launch(void* const* d_in, const int* in_sizes, int n_in,
                              void* d_out, int out_size, void* d_ws, size_t ws_size,
                              hipStream_t stream) {
    const float* x     = (const float*)d_in[0];
    const float* Wq    = (const float*)d_in[1];
    const float* Wk    = (const float*)d_in[2];
    const float* Wv    = (const float*)d_in[3];
    const float* rel_h = (const float*)d_in[4];
    const float* rel_w = (const float*)d_in[5];
    const float* agg_g1 = (const float*)d_in[6];
    const float* agg_b1 = (const float*)d_in[7];
    const float* agg_m1 = (const float*)d_in[8];
    const float* agg_v1 = (const float*)d_in[9];
    const float* agg_W  = (const float*)d_in[10];
    const float* agg_g2 = (const float*)d_in[11];
    const float* agg_b2 = (const float*)d_in[12];
    const float* agg_m2 = (const float*)d_in[13];
    const float* agg_v2 = (const float*)d_in[14];
    const float* se_Win = (const float*)d_in[15];
    const float* se_g_in = (const float*)d_in[16];
    const float* se_b_in = (const float*)d_in[17];
    const float* se_m_in = (const float*)d_in[18];
    const float* se_v_in = (const float*)d_in[19];
    const float* se_fc1  = (const float*)d_in[20];
    const float* se_fc2  = (const float*)d_in[21];
    const float* se_Wout = (const float*)d_in[22];
    const float* se_g_out = (const float*)d_in[23];
    const float* se_b_out = (const float*)d_in[24];
    const float* se_m_out = (const float*)d_in[25];
    const float* se_v_out = (const float*)d_in[26];

    float* ws = (float*)d_ws;
    const size_t NQ = (size_t)BB * HW * CC;   // 3,211,264
    float* q_ws = ws;
    float* k_ws = q_ws + NQ;
    float* v_ws = k_ws + NQ;
    float* ao_ws = v_ws + NQ;
    float* y2_ws = q_ws;              // alias: q dead after attention
    float* s_ws = ao_ws + NQ;
    float* psum = s_ws + (size_t)BB * HW * 16;
    float* g_ws = psum + 64;

    qkv_gemm<<<dim3(49, 4, 12), 256, 0, stream>>>(x, Wq, Wk, Wv, q_ws, k_ws, v_ws);
    attn_kernel<<<dim3(12544), 256, 0, stream>>>(q_ws, k_ws, v_ws, rel_h, rel_w, ao_ws);
    agg_gemm<<<dim3(49, 4, 4), 256, 0, stream>>>(ao_ws, agg_W,
        agg_g1, agg_b1, agg_m1, agg_v1, agg_g2, agg_b2, agg_m2, agg_v2, y2_ws);
    zero64<<<1, 64, 0, stream>>>(psum);
    se_in_kernel<<<dim3(196, 4), 256, 0, stream>>>(y2_ws, se_Win,
        se_g_in, se_b_in, se_m_in, se_v_in, s_ws, psum);
    se_gate<<<1, 64, 0, stream>>>(psum, se_fc1, se_fc2, g_ws);
    se_out_kernel<<<dim3(49, 64, 4), 256, 0, stream>>>(s_ws, g_ws, se_Wout,
        se_g_out, se_b_out, se_m_out, se_v_out, (float*)d_out);
}

// Round 3
// 278.159 us; speedup vs baseline: 1.7753x; 1.7753x over previous
//
#include <hip/hip_runtime.h>
#include <hip/hip_bf16.h>

#define HW 3136
#define HH 56
#define WW 56
#define BB 4
#define CC 256
#define HD 128

// attention tile geometry
#define TH 4
#define TW 8
#define WR 8    // TH+4
#define WC 12   // TW+4
#define WPX 96  // WR*WC
#define KSTR 132  // floats per window pixel in LDS (pad 128->132)
#define SSTR 33   // score buffer stride

// ---------------- K1: q/k/v 1x1 conv (GEMM), out layout [b][pixel][o] fp32 ----
__global__ __launch_bounds__(256) void qkv_gemm(
    const float* __restrict__ x,
    const float* __restrict__ Wq,
    const float* __restrict__ Wk,
    const float* __restrict__ Wv,
    float* __restrict__ q_ws, float* __restrict__ k_ws, float* __restrict__ v_ws)
{
    int wsel = blockIdx.z >> 2;      // 0:q 1:k 2:v
    int b = blockIdx.z & 3;
    const float* Wm = (wsel == 0) ? Wq : ((wsel == 1) ? Wk : Wv);
    float* outp = (wsel == 0) ? q_ws : ((wsel == 1) ? k_ws : v_ws);
    int p0 = blockIdx.x * 64, o0 = blockIdx.y * 64;

    __shared__ float As[16][68];
    __shared__ float Bs[16][68];
    int t = threadIdx.x;
    int o4 = (t & 15) * 4, p4g = (t >> 4) * 4;
    float acc[4][4] = {};
    const float* xb = x + (size_t)b * CC * HW;

    for (int c0 = 0; c0 < 256; c0 += 16) {
        {   // A tile: As[kk][p] = x[b][c0+kk][p0+p]
            int kk = t >> 4, pp = (t & 15) * 4;
            float4 f = *(const float4*)(xb + (size_t)(c0 + kk) * HW + p0 + pp);
            *(float4*)&As[kk][pp] = f;
        }
        {   // B tile: Bs[kk][o] = W[o0+o][c0+kk]
            int oo = t >> 2, k4 = (t & 3) * 4;
            float4 u = *(const float4*)(Wm + (size_t)(o0 + oo) * 256 + c0 + k4);
            Bs[k4 + 0][oo] = u.x; Bs[k4 + 1][oo] = u.y;
            Bs[k4 + 2][oo] = u.z; Bs[k4 + 3][oo] = u.w;
        }
        __syncthreads();
#pragma unroll
        for (int kk = 0; kk < 16; kk++) {
            float4 a4 = *(float4*)&As[kk][p4g];
            float4 b4 = *(float4*)&Bs[kk][o4];
            float a[4] = {a4.x, a4.y, a4.z, a4.w};
            float bb[4] = {b4.x, b4.y, b4.z, b4.w};
#pragma unroll
            for (int i = 0; i < 4; i++)
#pragma unroll
                for (int j = 0; j < 4; j++) acc[i][j] += a[i] * bb[j];
        }
        __syncthreads();
    }
    float* ob = outp + (size_t)b * HW * CC;
#pragma unroll
    for (int i = 0; i < 4; i++) {
        float4 r = make_float4(acc[i][0], acc[i][1], acc[i][2], acc[i][3]);
        *(float4*)(ob + (size_t)(p0 + p4g + i) * CC + o0 + o4) = r;
    }
}

// ---------------- K2: local attention, LDS-tiled, block per (b,head,4x8 tile)
__global__ __launch_bounds__(256) void attn_kernel(
    const float* __restrict__ q_ws, const float* __restrict__ k_ws,
    const float* __restrict__ v_ws,
    const float* __restrict__ rel_h, const float* __restrict__ rel_w,
    float* __restrict__ ao_ws)
{
    __shared__ float kwin[WPX * KSTR];   // 50688 B; holds k, then reused for v
    __shared__ float sbuf[32 * SSTR];    // 4224 B: 25 dots + 5 bias dots per px
    __shared__ float relT[5 * KSTR];     // 2640 B: rel transposed [tap][c]

    int t = threadIdx.x;
    int tile = blockIdx.x;               // 0..97 (14 row-tiles x 7 col-tiles)
    int n = blockIdx.y;
    int b = blockIdx.z;
    int tr = tile / 7, tc = tile - tr * 7;
    int h0 = tr * TH, w0 = tc * TW;
    const float* rel = (n == 0) ? rel_h : rel_w;
    const size_t base = (size_t)b * HW * CC + n * HD;

    // ---- stage k window (zero-filled outside image) + relT ----
    {
        int c4 = t & 31, pw0 = t >> 5;
#pragma unroll
        for (int it = 0; it < 12; it++) {
            int pw = pw0 + it * 8;
            int wr = pw / 12, wc = pw - wr * 12;
            int gh = h0 + wr - 2, gw = w0 + wc - 2;
            float4 f = make_float4(0.f, 0.f, 0.f, 0.f);
            if (gh >= 0 && gh < HH && gw >= 0 && gw < WW)
                f = *(const float4*)(k_ws + base + (size_t)(gh * WW + gw) * CC + c4 * 4);
            *(float4*)&kwin[pw * KSTR + c4 * 4] = f;
        }
        if (t < 128) {
#pragma unroll
            for (int tt = 0; tt < 5; tt++)
                relT[tt * KSTR + t] = rel[t * 5 + tt];
        }
    }
    __syncthreads();

    int px = t >> 3, c4g = t & 7;        // px 0..31, 8 lanes per pixel
    int pr = px >> 3, pc = px & 7;       // pr 0..3, pc 0..7
    int ghp = h0 + pr, gwp = w0 + pc;
    const size_t pbase = base + (size_t)(ghp * WW + gwp) * CC;

    // q chunks for this thread's 16 channels (c4g, c4g+8, c4g+16, c4g+24)
    float4 q4[4];
#pragma unroll
    for (int i = 0; i < 4; i++)
        q4[i] = *(const float4*)(q_ws + pbase + (c4g + 8 * i) * 4);

    // ---- partial dots: 25 taps + 5 rel-bias taps ----
    float acc[30];
#pragma unroll
    for (int tt = 0; tt < 30; tt++) acc[tt] = 0.f;
#pragma unroll
    for (int i = 0; i < 4; i++) {
        float4 q = q4[i];
        int co = (c4g + 8 * i) * 4;
#pragma unroll
        for (int tt = 0; tt < 25; tt++) {
            int di = tt / 5, dj = tt - 5 * (tt / 5);
            int wpx = (pr + di) * WC + pc + dj;
            float4 k4 = *(const float4*)&kwin[wpx * KSTR + co];
            acc[tt] += q.x * k4.x + q.y * k4.y + q.z * k4.z + q.w * k4.w;
        }
#pragma unroll
        for (int tt = 0; tt < 5; tt++) {
            float4 r4 = *(const float4*)&relT[tt * KSTR + co];
            acc[25 + tt] += q.x * r4.x + q.y * r4.y + q.z * r4.z + q.w * r4.w;
        }
    }
    // butterfly over the 8 lanes sharing a pixel
#pragma unroll
    for (int tt = 0; tt < 30; tt++) {
#pragma unroll
        for (int m = 1; m < 8; m <<= 1)
            acc[tt] += __shfl_xor(acc[tt], m, 64);
    }
    // spread writes across lanes, compile-time acc index (no spills)
#pragma unroll
    for (int tt = 0; tt < 30; tt++)
        if ((tt & 7) == c4g) sbuf[px * SSTR + tt] = acc[tt];
    __syncthreads();

    // ---- stage v into same buffer; threads 0..31 do softmax meanwhile ----
    {
        int c4 = t & 31, pw0 = t >> 5;
#pragma unroll
        for (int it = 0; it < 12; it++) {
            int pw = pw0 + it * 8;
            int wr = pw / 12, wc = pw - wr * 12;
            int gh = h0 + wr - 2, gw = w0 + wc - 2;
            float4 f = make_float4(0.f, 0.f, 0.f, 0.f);
            if (gh >= 0 && gh < HH && gw >= 0 && gw < WW)
                f = *(const float4*)(v_ws + base + (size_t)(gh * WW + gw) * CC + c4 * 4);
            *(float4*)&kwin[pw * KSTR + c4 * 4] = f;
        }
    }
    if (t < 32) {
        float s[25], b5[5];
#pragma unroll
        for (int tt = 0; tt < 25; tt++) s[tt] = sbuf[t * SSTR + tt];
#pragma unroll
        for (int tt = 0; tt < 5; tt++) b5[tt] = sbuf[t * SSTR + 25 + tt];
        const float inv = 0.08838834764831845f;  // 1/sqrt(128)
        float mx = -1e30f;
#pragma unroll
        for (int tt = 0; tt < 25; tt++) {
            int di = tt / 5, dj = tt - 5 * (tt / 5);
            s[tt] = (s[tt] + ((n == 0) ? b5[di] : b5[dj])) * inv;
            mx = fmaxf(mx, s[tt]);
        }
        float sum = 0.f;
#pragma unroll
        for (int tt = 0; tt < 25; tt++) { s[tt] = __expf(s[tt] - mx); sum += s[tt]; }
        float rs = 1.f / sum;
#pragma unroll
        for (int tt = 0; tt < 25; tt++) sbuf[t * SSTR + tt] = s[tt] * rs;
    }
    __syncthreads();

    // ---- weighted v aggregation ----
    float w25[25];
#pragma unroll
    for (int tt = 0; tt < 25; tt++) w25[tt] = sbuf[px * SSTR + tt];
    float4 oacc[4];
#pragma unroll
    for (int i = 0; i < 4; i++) oacc[i] = make_float4(0.f, 0.f, 0.f, 0.f);
#pragma unroll
    for (int tt = 0; tt < 25; tt++) {
        int di = tt / 5, dj = tt - 5 * (tt / 5);
        int wpx = (pr + di) * WC + pc + dj;
        float a = w25[tt];
#pragma unroll
        for (int i = 0; i < 4; i++) {
            float4 v4 = *(const float4*)&kwin[wpx * KSTR + (c4g + 8 * i) * 4];
            oacc[i].x += a * v4.x; oacc[i].y += a * v4.y;
            oacc[i].z += a * v4.z; oacc[i].w += a * v4.w;
        }
    }
#pragma unroll
    for (int i = 0; i < 4; i++)
        *(float4*)(ao_ws + pbase + (c4g + 8 * i) * 4) = oacc[i];
}

// ---------------- K3: BN1+ReLU -> agg GEMM -> BN2, [b][p][o] fp32 ------------
__global__ __launch_bounds__(256) void agg_gemm(
    const float* __restrict__ ao, const float* __restrict__ aggW,
    const float* __restrict__ g1, const float* __restrict__ b1,
    const float* __restrict__ m1, const float* __restrict__ v1,
    const float* __restrict__ g2, const float* __restrict__ b2,
    const float* __restrict__ m2, const float* __restrict__ v2,
    float* __restrict__ y2)
{
    int b = blockIdx.z;
    int p0 = blockIdx.x * 64, o0 = blockIdx.y * 64;
    __shared__ float As[16][68];
    __shared__ float Bs[16][68];
    int t = threadIdx.x;
    int o4 = (t & 15) * 4, p4g = (t >> 4) * 4;
    float acc[4][4] = {};
    const float* aob = ao + (size_t)b * HW * CC;

    for (int c0 = 0; c0 < 256; c0 += 16) {
        {   // A tile with fused BN1+ReLU, transposed store
            int p = t >> 2, k4 = (t & 3) * 4;
            float4 a = *(const float4*)(aob + (size_t)(p0 + p) * CC + c0 + k4);
            float av[4] = {a.x, a.y, a.z, a.w};
#pragma unroll
            for (int u = 0; u < 4; u++) {
                int c = c0 + k4 + u;
                float sc = g1[c] * rsqrtf(v1[c] + 1e-5f);
                float val = (av[u] - m1[c]) * sc + b1[c];
                As[k4 + u][p] = fmaxf(val, 0.f);
            }
        }
        {
            int oo = t >> 2, k4 = (t & 3) * 4;
            float4 u = *(const float4*)(aggW + (size_t)(o0 + oo) * 256 + c0 + k4);
            Bs[k4 + 0][oo] = u.x; Bs[k4 + 1][oo] = u.y;
            Bs[k4 + 2][oo] = u.z; Bs[k4 + 3][oo] = u.w;
        }
        __syncthreads();
#pragma unroll
        for (int kk = 0; kk < 16; kk++) {
            float4 a4 = *(float4*)&As[kk][p4g];
            float4 b4 = *(float4*)&Bs[kk][o4];
            float a[4] = {a4.x, a4.y, a4.z, a4.w};
            float bb[4] = {b4.x, b4.y, b4.z, b4.w};
#pragma unroll
            for (int i = 0; i < 4; i++)
#pragma unroll
                for (int j = 0; j < 4; j++) acc[i][j] += a[i] * bb[j];
        }
        __syncthreads();
    }
    float* yb = y2 + (size_t)b * HW * CC;
#pragma unroll
    for (int i = 0; i < 4; i++) {
        float r[4];
#pragma unroll
        for (int j = 0; j < 4; j++) {
            int o = o0 + o4 + j;
            float sc = g2[o] * rsqrtf(v2[o] + 1e-5f);
            r[j] = (acc[i][j] - m2[o]) * sc + b2[o];
        }
        *(float4*)(yb + (size_t)(p0 + p4g + i) * CC + o0 + o4) =
            make_float4(r[0], r[1], r[2], r[3]);
    }
}

// ---------------- K4: SE squeeze conv + partial mean -------------------------
__global__ __launch_bounds__(256) void se_in_kernel(
    const float* __restrict__ y2, const float* __restrict__ se_Win,
    const float* __restrict__ gin, const float* __restrict__ bin,
    const float* __restrict__ min_, const float* __restrict__ vin,
    float* __restrict__ s_ws, float* __restrict__ psum)
{
    int b = blockIdx.y;
    int p0 = blockIdx.x * 16;
    __shared__ float yt[16][257];
    __shared__ float wt[16][257];
    __shared__ float red[16][17];
    int t = threadIdx.x;
    const float* yb = y2 + (size_t)(b * HW + p0) * CC;
#pragma unroll
    for (int i = 0; i < 16; i++) yt[i][t] = yb[(size_t)i * CC + t];
#pragma unroll
    for (int i = 0; i < 16; i++) wt[i][t] = se_Win[i * 256 + t];
    __syncthreads();
    int p = t >> 4, j = t & 15;
    float dot = 0.f;
#pragma unroll 8
    for (int c = 0; c < 256; c++) dot += yt[p][c] * wt[j][c];
    float sc = gin[j] * rsqrtf(vin[j] + 1e-5f);
    float sv = fmaxf((dot - min_[j]) * sc + bin[j], 0.f);
    s_ws[(size_t)(b * HW + p0 + p) * 16 + j] = sv;
    red[p][j] = sv;
    __syncthreads();
    if (t < 16) {
        float sm = 0.f;
#pragma unroll
        for (int pp = 0; pp < 16; pp++) sm += red[pp][t];
        atomicAdd(&psum[b * 16 + t], sm);
    }
}

__global__ void zero64(float* p) { p[threadIdx.x] = 0.f; }

// ---------------- K5: SE gate ------------------------------------------------
__global__ void se_gate(const float* __restrict__ psum,
                        const float* __restrict__ fc1,
                        const float* __restrict__ fc2,
                        float* __restrict__ g_ws)
{
    int t = threadIdx.x;
    if (t >= 64) return;
    int b = t >> 4, j = t & 15;
    float h = 0.f;
#pragma unroll
    for (int jj = 0; jj < 16; jj++)
        h += (psum[b * 16 + jj] * (1.f / 3136.f)) * fc1[jj];
    h = fmaxf(h, 0.f);
    float z = h * fc2[j];
    g_ws[t] = 1.f / (1.f + __expf(-z));
}

// ---------------- K6: SE excite conv + BN + fp32 store (NCHW) ----------------
__global__ __launch_bounds__(256) void se_out_kernel(
    const float* __restrict__ s_ws, const float* __restrict__ g_ws,
    const float* __restrict__ se_Wout,
    const float* __restrict__ gout, const float* __restrict__ bout,
    const float* __restrict__ mout, const float* __restrict__ vout,
    float* __restrict__ out)
{
    int b = blockIdx.z;
    int o0 = blockIdx.y * 4;
    int p0 = blockIdx.x * 64;
    __shared__ float st[64][17];
    __shared__ float wg[4][16];
    int t = threadIdx.x;
#pragma unroll
    for (int i = 0; i < 4; i++) {
        int idx = i * 256 + t;
        st[idx >> 4][idx & 15] = s_ws[(size_t)(b * HW + p0 + (idx >> 4)) * 16 + (idx & 15)];
    }
    if (t < 64) {
        int ol = t >> 4, j = t & 15;
        wg[ol][j] = se_Wout[(o0 + ol) * 16 + j] * g_ws[b * 16 + j];
    }
    __syncthreads();
    int ol = t >> 6, pl = t & 63;
    float dot = 0.f;
#pragma unroll
    for (int j = 0; j < 16; j++) dot += st[pl][j] * wg[ol][j];
    int o = o0 + ol;
    float sc = gout[o] * rsqrtf(vout[o] + 1e-5f);
    float r = (dot - mout[o]) * sc + bout[o];
    out[((size_t)(b * 256 + o)) * HW + p0 + pl] = r;
}

extern "C" void kernel_launch(void* const* d_in, const int* in_sizes, int n_in,
                              void* d_out, int out_size, void* d_ws, size_t ws_size,
                              hipStream_t stream) {
    const float* x     = (const float*)d_in[0];
    const float* Wq    = (const float*)d_in[1];
    const float* Wk    = (const float*)d_in[2];
    const float* Wv    = (const float*)d_in[3];
    const float* rel_h = (const float*)d_in[4];
    const float* rel_w = (const float*)d_in[5];
    const float* agg_g1 = (const float*)d_in[6];
    const float* agg_b1 = (const float*)d_in[7];
    const float* agg_m1 = (const float*)d_in[8];
    const float* agg_v1 = (const float*)d_in[9];
    const float* agg_W  = (const float*)d_in[10];
    const float* agg_g2 = (const float*)d_in[11];
    const float* agg_b2 = (const float*)d_in[12];
    const float* agg_m2 = (const float*)d_in[13];
    const float* agg_v2 = (const float*)d_in[14];
    const float* se_Win = (const float*)d_in[15];
    const float* se_g_in = (const float*)d_in[16];
    const float* se_b_in = (const float*)d_in[17];
    const float* se_m_in = (const float*)d_in[18];
    const float* se_v_in = (const float*)d_in[19];
    const float* se_fc1  = (const float*)d_in[20];
    const float* se_fc2  = (const float*)d_in[21];
    const float* se_Wout = (const float*)d_in[22];
    const float* se_g_out = (const float*)d_in[23];
    const float* se_b_out = (const float*)d_in[24];
    const float* se_m_out = (const float*)d_in[25];
    const float* se_v_out = (const float*)d_in[26];

    float* ws = (float*)d_ws;
    const size_t NQ = (size_t)BB * HW * CC;   // 3,211,264
    float* q_ws = ws;
    float* k_ws = q_ws + NQ;
    float* v_ws = k_ws + NQ;
    float* ao_ws = v_ws + NQ;
    float* y2_ws = q_ws;              // alias: q dead after attention
    float* s_ws = ao_ws + NQ;
    float* psum = s_ws + (size_t)BB * HW * 16;
    float* g_ws = psum + 64;

    qkv_gemm<<<dim3(49, 4, 12), 256, 0, stream>>>(x, Wq, Wk, Wv, q_ws, k_ws, v_ws);
    attn_kernel<<<dim3(98, 2, 4), 256, 0, stream>>>(q_ws, k_ws, v_ws, rel_h, rel_w, ao_ws);
    agg_gemm<<<dim3(49, 4, 4), 256, 0, stream>>>(ao_ws, agg_W,
        agg_g1, agg_b1, agg_m1, agg_v1, agg_g2, agg_b2, agg_m2, agg_v2, y2_ws);
    zero64<<<1, 64, 0, stream>>>(psum);
    se_in_kernel<<<dim3(196, 4), 256, 0, stream>>>(y2_ws, se_Win,
        se_g_in, se_b_in, se_m_in, se_v_in, s_ws, psum);
    se_gate<<<1, 64, 0, stream>>>(psum, se_fc1, se_fc2, g_ws);
    se_out_kernel<<<dim3(49, 64, 4), 256, 0, stream>>>(s_ws, g_ws, se_Wout,
        se_g_out, se_b_out, se_m_out, se_v_out, (float*)d_out);
}

// Round 6
// 213.217 us; speedup vs baseline: 2.3161x; 1.3046x over previous
//
#include <hip/hip_runtime.h>
#include <hip/hip_bf16.h>

#define HW 3136
#define HH 56
#define WW 56
#define BB 4
#define CC 256
#define HD 128

// attention tile geometry
#define TH 4
#define TW 8
#define WR 8    // TH+4
#define WC 12   // TW+4
#define WPX 96  // WR*WC
#define KSTR 132  // floats per window pixel in LDS (pad 128->132)
#define SSTR 33   // score buffer stride

// MFMA GEMM geometry: 128x128 tile, BK=64, LDS row = 64 bf16 + pad -> 72 (144 B)
#define ASTR 72

typedef __attribute__((ext_vector_type(8))) short bf16x8;
typedef __attribute__((ext_vector_type(4))) float f32x4;

__device__ __forceinline__ unsigned short f2bf(float f) {
    unsigned int u; __builtin_memcpy(&u, &f, 4);
    unsigned int r = u + 0x7FFFu + ((u >> 16) & 1u);   // RNE
    return (unsigned short)(r >> 16);
}

// ---------------- K0a: x [b][c][p] fp32 -> xt [(b*HW+p)][c] bf16 -------------
__global__ __launch_bounds__(256) void xt_cvt(const float* __restrict__ x,
                                              unsigned short* __restrict__ xt)
{
    int b = blockIdx.z;
    int c0 = blockIdx.y * 64;
    int p0 = blockIdx.x * 64;
    __shared__ float tile[64][65];   // [channel][pixel]
    int t = threadIdx.x;
    int p4 = t & 15, cl = t >> 4;
    const float* xb = x + ((size_t)b * CC + c0) * HW + p0;
#pragma unroll
    for (int i = 0; i < 4; i++) {
        int c = cl + 16 * i;
        float4 f = *(const float4*)(xb + (size_t)c * HW + p4 * 4);
        tile[c][p4 * 4 + 0] = f.x; tile[c][p4 * 4 + 1] = f.y;
        tile[c][p4 * 4 + 2] = f.z; tile[c][p4 * 4 + 3] = f.w;
    }
    __syncthreads();
    int c2 = t & 31, pl = t >> 5;
    unsigned short* xo = xt + ((size_t)b * HW + p0) * CC + c0;
#pragma unroll
    for (int i = 0; i < 8; i++) {
        int p = pl + 8 * i;
        // FIX(r5): read tile[channel][pixel], not tile[pixel][channel]
        float a = tile[2 * c2][p], bb = tile[2 * c2 + 1][p];
        unsigned int pk = (unsigned int)f2bf(a) | ((unsigned int)f2bf(bb) << 16);
        *(unsigned int*)(xo + (size_t)p * CC + 2 * c2) = pk;
    }
}

// ---------------- K0b: weights fp32 -> bf16 (Wq,Wk,Wv,aggW) ------------------
__global__ __launch_bounds__(256) void wcvt(const float* __restrict__ Wq,
                                            const float* __restrict__ Wk,
                                            const float* __restrict__ Wv,
                                            const float* __restrict__ Wa,
                                            unsigned short* __restrict__ wb)
{
    const float* srcs[4] = {Wq, Wk, Wv, Wa};
    const float* s = srcs[blockIdx.y];
    int idx = blockIdx.x * 256 + threadIdx.x;       // 0..16383
    float4 f = *(const float4*)(s + (size_t)idx * 4);
    uint2 pk;
    pk.x = (unsigned int)f2bf(f.x) | ((unsigned int)f2bf(f.y) << 16);
    pk.y = (unsigned int)f2bf(f.z) | ((unsigned int)f2bf(f.w) << 16);
    *(uint2*)(wb + (size_t)blockIdx.y * 65536 + (size_t)idx * 4) = pk;
}

// ---------------- K1: qkv via MFMA bf16, M = flattened (b*HW+p) --------------
// grid: (98, 2, 3)  -> x: M-tile (128 of 12544), y: o-tile (128 of 256), z: wsel
__global__ __launch_bounds__(256) void qkv_mfma(
    const unsigned short* __restrict__ xt, const unsigned short* __restrict__ wqkv,
    float* __restrict__ q_ws, float* __restrict__ k_ws, float* __restrict__ v_ws)
{
    int wsel = blockIdx.z;
    float* outp = (wsel == 0) ? q_ws : ((wsel == 1) ? k_ws : v_ws);
    int gp0 = blockIdx.x * 128, o0 = blockIdx.y * 128;

    __shared__ unsigned short As[128 * ASTR];
    __shared__ unsigned short Bs[128 * ASTR];
    const unsigned short* xb = xt + (size_t)gp0 * CC;
    const unsigned short* wbp = wqkv + (size_t)wsel * 65536 + (size_t)o0 * CC;

    int t = threadIdx.x;
    int wave = t >> 6, lane = t & 63;
    int mo = (wave & 1) * 64, no = (wave >> 1) * 64;
    int lm = lane & 15, lq = lane >> 4;
    int sr = t >> 3, sc = t & 7;

    f32x4 acc[4][4];
#pragma unroll
    for (int i = 0; i < 4; i++)
#pragma unroll
        for (int j = 0; j < 4; j++) acc[i][j] = (f32x4){0.f, 0.f, 0.f, 0.f};

    for (int k0 = 0; k0 < 256; k0 += 64) {
#pragma unroll
        for (int i = 0; i < 4; i++) {
            int r = sr + 32 * i;
            *(uint4*)&As[r * ASTR + sc * 8] = *(const uint4*)(xb + (size_t)r * CC + k0 + sc * 8);
            *(uint4*)&Bs[r * ASTR + sc * 8] = *(const uint4*)(wbp + (size_t)r * CC + k0 + sc * 8);
        }
        __syncthreads();
#pragma unroll
        for (int ks = 0; ks < 64; ks += 32) {
            bf16x8 af[4], bfr[4];
#pragma unroll
            for (int i = 0; i < 4; i++)
                af[i] = *(bf16x8*)&As[(mo + 16 * i + lm) * ASTR + ks + lq * 8];
#pragma unroll
            for (int j = 0; j < 4; j++)
                bfr[j] = *(bf16x8*)&Bs[(no + 16 * j + lm) * ASTR + ks + lq * 8];
#pragma unroll
            for (int i = 0; i < 4; i++)
#pragma unroll
                for (int j = 0; j < 4; j++)
                    acc[i][j] = __builtin_amdgcn_mfma_f32_16x16x32_bf16(
                        af[i], bfr[j], acc[i][j], 0, 0, 0);
        }
        __syncthreads();
    }
    float* ob = outp + (size_t)gp0 * CC + o0;
#pragma unroll
    for (int i = 0; i < 4; i++)
#pragma unroll
        for (int j = 0; j < 4; j++)
#pragma unroll
            for (int r = 0; r < 4; r++) {
                int m = mo + 16 * i + lq * 4 + r;
                int n = no + 16 * j + lm;
                ob[(size_t)m * CC + n] = acc[i][j][r];
            }
}

// ---------------- K3: agg via MFMA bf16, M flattened; BN1+ReLU / BN2 fused ---
// grid: (98, 2)
__global__ __launch_bounds__(256) void agg_mfma(
    const float* __restrict__ ao, const unsigned short* __restrict__ wagg,
    const float* __restrict__ g1, const float* __restrict__ b1,
    const float* __restrict__ m1, const float* __restrict__ v1,
    const float* __restrict__ g2, const float* __restrict__ b2,
    const float* __restrict__ m2, const float* __restrict__ v2,
    float* __restrict__ y2)
{
    int gp0 = blockIdx.x * 128, o0 = blockIdx.y * 128;

    __shared__ unsigned short As[128 * ASTR];
    __shared__ unsigned short Bs[128 * ASTR];
    __shared__ float s1[256], o1[256], s2[256], o2[256];

    int t = threadIdx.x;
    {
        float sc1 = g1[t] * rsqrtf(v1[t] + 1e-5f);
        s1[t] = sc1; o1[t] = b1[t] - m1[t] * sc1;
        float sc2 = g2[t] * rsqrtf(v2[t] + 1e-5f);
        s2[t] = sc2; o2[t] = b2[t] - m2[t] * sc2;
    }

    const float* aob = ao + (size_t)gp0 * CC;
    const unsigned short* wbp = wagg + (size_t)o0 * CC;

    int wave = t >> 6, lane = t & 63;
    int mo = (wave & 1) * 64, no = (wave >> 1) * 64;
    int lm = lane & 15, lq = lane >> 4;
    int sr = t >> 3, sc = t & 7;

    f32x4 acc[4][4];
#pragma unroll
    for (int i = 0; i < 4; i++)
#pragma unroll
        for (int j = 0; j < 4; j++) acc[i][j] = (f32x4){0.f, 0.f, 0.f, 0.f};

    __syncthreads();   // s1/o1 ready before first use

    for (int k0 = 0; k0 < 256; k0 += 64) {
#pragma unroll
        for (int i = 0; i < 4; i++) {
            int r = sr + 32 * i;
            int cb = k0 + sc * 8;
            const float* arow = aob + (size_t)r * CC + cb;
            float4 f0 = *(const float4*)(arow);
            float4 f1 = *(const float4*)(arow + 4);
            float e[8] = {f0.x, f0.y, f0.z, f0.w, f1.x, f1.y, f1.z, f1.w};
            unsigned short pk[8];
#pragma unroll
            for (int u = 0; u < 8; u++) {
                float vv = fmaxf(e[u] * s1[cb + u] + o1[cb + u], 0.f);
                pk[u] = f2bf(vv);
            }
            *(uint4*)&As[r * ASTR + sc * 8] = *(uint4*)pk;
            *(uint4*)&Bs[r * ASTR + sc * 8] = *(const uint4*)(wbp + (size_t)r * CC + k0 + sc * 8);
        }
        __syncthreads();
#pragma unroll
        for (int ks = 0; ks < 64; ks += 32) {
            bf16x8 af[4], bfr[4];
#pragma unroll
            for (int i = 0; i < 4; i++)
                af[i] = *(bf16x8*)&As[(mo + 16 * i + lm) * ASTR + ks + lq * 8];
#pragma unroll
            for (int j = 0; j < 4; j++)
                bfr[j] = *(bf16x8*)&Bs[(no + 16 * j + lm) * ASTR + ks + lq * 8];
#pragma unroll
            for (int i = 0; i < 4; i++)
#pragma unroll
                for (int j = 0; j < 4; j++)
                    acc[i][j] = __builtin_amdgcn_mfma_f32_16x16x32_bf16(
                        af[i], bfr[j], acc[i][j], 0, 0, 0);
        }
        __syncthreads();
    }
    float* yb = y2 + (size_t)gp0 * CC + o0;
#pragma unroll
    for (int i = 0; i < 4; i++)
#pragma unroll
        for (int j = 0; j < 4; j++)
#pragma unroll
            for (int r = 0; r < 4; r++) {
                int m = mo + 16 * i + lq * 4 + r;
                int n = no + 16 * j + lm;
                yb[(size_t)m * CC + n] = acc[i][j][r] * s2[o0 + n] + o2[o0 + n];
            }
}

// ---------------- K2: local attention, LDS-tiled, block per (b,head,4x8 tile)
__global__ __launch_bounds__(256) void attn_kernel(
    const float* __restrict__ q_ws, const float* __restrict__ k_ws,
    const float* __restrict__ v_ws,
    const float* __restrict__ rel_h, const float* __restrict__ rel_w,
    float* __restrict__ ao_ws)
{
    __shared__ float kwin[WPX * KSTR];   // 50688 B; holds k, then reused for v
    __shared__ float sbuf[32 * SSTR];
    __shared__ float relT[5 * KSTR];

    int t = threadIdx.x;
    int tile = blockIdx.x;
    int n = blockIdx.y;
    int b = blockIdx.z;
    int tr = tile / 7, tc = tile - tr * 7;
    int h0 = tr * TH, w0 = tc * TW;
    const float* rel = (n == 0) ? rel_h : rel_w;
    const size_t base = (size_t)b * HW * CC + n * HD;

    {
        int c4 = t & 31, pw0 = t >> 5;
#pragma unroll
        for (int it = 0; it < 12; it++) {
            int pw = pw0 + it * 8;
            int wr = pw / 12, wc = pw - wr * 12;
            int gh = h0 + wr - 2, gw = w0 + wc - 2;
            float4 f = make_float4(0.f, 0.f, 0.f, 0.f);
            if (gh >= 0 && gh < HH && gw >= 0 && gw < WW)
                f = *(const float4*)(k_ws + base + (size_t)(gh * WW + gw) * CC + c4 * 4);
            *(float4*)&kwin[pw * KSTR + c4 * 4] = f;
        }
        if (t < 128) {
#pragma unroll
            for (int tt = 0; tt < 5; tt++)
                relT[tt * KSTR + t] = rel[t * 5 + tt];
        }
    }
    __syncthreads();

    int px = t >> 3, c4g = t & 7;
    int pr = px >> 3, pc = px & 7;
    int ghp = h0 + pr, gwp = w0 + pc;
    const size_t pbase = base + (size_t)(ghp * WW + gwp) * CC;

    float4 q4[4];
#pragma unroll
    for (int i = 0; i < 4; i++)
        q4[i] = *(const float4*)(q_ws + pbase + (c4g + 8 * i) * 4);

    float acc[30];
#pragma unroll
    for (int tt = 0; tt < 30; tt++) acc[tt] = 0.f;
#pragma unroll
    for (int i = 0; i < 4; i++) {
        float4 q = q4[i];
        int co = (c4g + 8 * i) * 4;
#pragma unroll
        for (int tt = 0; tt < 25; tt++) {
            int di = tt / 5, dj = tt - 5 * (tt / 5);
            int wpx = (pr + di) * WC + pc + dj;
            float4 k4 = *(const float4*)&kwin[wpx * KSTR + co];
            acc[tt] += q.x * k4.x + q.y * k4.y + q.z * k4.z + q.w * k4.w;
        }
#pragma unroll
        for (int tt = 0; tt < 5; tt++) {
            float4 r4 = *(const float4*)&relT[tt * KSTR + co];
            acc[25 + tt] += q.x * r4.x + q.y * r4.y + q.z * r4.z + q.w * r4.w;
        }
    }
#pragma unroll
    for (int tt = 0; tt < 30; tt++) {
#pragma unroll
        for (int m = 1; m < 8; m <<= 1)
            acc[tt] += __shfl_xor(acc[tt], m, 64);
    }
#pragma unroll
    for (int tt = 0; tt < 30; tt++)
        if ((tt & 7) == c4g) sbuf[px * SSTR + tt] = acc[tt];
    __syncthreads();

    {
        int c4 = t & 31, pw0 = t >> 5;
#pragma unroll
        for (int it = 0; it < 12; it++) {
            int pw = pw0 + it * 8;
            int wr = pw / 12, wc = pw - wr * 12;
            int gh = h0 + wr - 2, gw = w0 + wc - 2;
            float4 f = make_float4(0.f, 0.f, 0.f, 0.f);
            if (gh >= 0 && gh < HH && gw >= 0 && gw < WW)
                f = *(const float4*)(v_ws + base + (size_t)(gh * WW + gw) * CC + c4 * 4);
            *(float4*)&kwin[pw * KSTR + c4 * 4] = f;
        }
    }
    if (t < 32) {
        float s[25], b5[5];
#pragma unroll
        for (int tt = 0; tt < 25; tt++) s[tt] = sbuf[t * SSTR + tt];
#pragma unroll
        for (int tt = 0; tt < 5; tt++) b5[tt] = sbuf[t * SSTR + 25 + tt];
        const float inv = 0.08838834764831845f;
        float mx = -1e30f;
#pragma unroll
        for (int tt = 0; tt < 25; tt++) {
            int di = tt / 5, dj = tt - 5 * (tt / 5);
            s[tt] = (s[tt] + ((n == 0) ? b5[di] : b5[dj])) * inv;
            mx = fmaxf(mx, s[tt]);
        }
        float sum = 0.f;
#pragma unroll
        for (int tt = 0; tt < 25; tt++) { s[tt] = __expf(s[tt] - mx); sum += s[tt]; }
        float rs = 1.f / sum;
#pragma unroll
        for (int tt = 0; tt < 25; tt++) sbuf[t * SSTR + tt] = s[tt] * rs;
    }
    __syncthreads();

    float w25[25];
#pragma unroll
    for (int tt = 0; tt < 25; tt++) w25[tt] = sbuf[px * SSTR + tt];
    float4 oacc[4];
#pragma unroll
    for (int i = 0; i < 4; i++) oacc[i] = make_float4(0.f, 0.f, 0.f, 0.f);
#pragma unroll
    for (int tt = 0; tt < 25; tt++) {
        int di = tt / 5, dj = tt - 5 * (tt / 5);
        int wpx = (pr + di) * WC + pc + dj;
        float a = w25[tt];
#pragma unroll
        for (int i = 0; i < 4; i++) {
            float4 v4 = *(const float4*)&kwin[wpx * KSTR + (c4g + 8 * i) * 4];
            oacc[i].x += a * v4.x; oacc[i].y += a * v4.y;
            oacc[i].z += a * v4.z; oacc[i].w += a * v4.w;
        }
    }
#pragma unroll
    for (int i = 0; i < 4; i++)
        *(float4*)(ao_ws + pbase + (c4g + 8 * i) * 4) = oacc[i];
}

// ---------------- K4: SE squeeze conv + partial mean -------------------------
__global__ __launch_bounds__(256) void se_in_kernel(
    const float* __restrict__ y2, const float* __restrict__ se_Win,
    const float* __restrict__ gin, const float* __restrict__ bin,
    const float* __restrict__ min_, const float* __restrict__ vin,
    float* __restrict__ s_ws, float* __restrict__ psum)
{
    int b = blockIdx.y;
    int p0 = blockIdx.x * 16;
    __shared__ float yt[16][257];
    __shared__ float wt[16][257];
    __shared__ float red[16][17];
    int t = threadIdx.x;
    const float* yb = y2 + (size_t)(b * HW + p0) * CC;
#pragma unroll
    for (int i = 0; i < 16; i++) yt[i][t] = yb[(size_t)i * CC + t];
#pragma unroll
    for (int i = 0; i < 16; i++) wt[i][t] = se_Win[i * 256 + t];
    __syncthreads();
    int p = t >> 4, j = t & 15;
    float dot = 0.f;
#pragma unroll 8
    for (int c = 0; c < 256; c++) dot += yt[p][c] * wt[j][c];
    float sc = gin[j] * rsqrtf(vin[j] + 1e-5f);
    float sv = fmaxf((dot - min_[j]) * sc + bin[j], 0.f);
    s_ws[(size_t)(b * HW + p0 + p) * 16 + j] = sv;
    red[p][j] = sv;
    __syncthreads();
    if (t < 16) {
        float sm = 0.f;
#pragma unroll
        for (int pp = 0; pp < 16; pp++) sm += red[pp][t];
        atomicAdd(&psum[b * 16 + t], sm);
    }
}

__global__ void zero64(float* p) { p[threadIdx.x] = 0.f; }

// ---------------- K5: SE gate ------------------------------------------------
__global__ void se_gate(const float* __restrict__ psum,
                        const float* __restrict__ fc1,
                        const float* __restrict__ fc2,
                        float* __restrict__ g_ws)
{
    int t = threadIdx.x;
    if (t >= 64) return;
    int b = t >> 4, j = t & 15;
    float h = 0.f;
#pragma unroll
    for (int jj = 0; jj < 16; jj++)
        h += (psum[b * 16 + jj] * (1.f / 3136.f)) * fc1[jj];
    h = fmaxf(h, 0.f);
    float z = h * fc2[j];
    g_ws[t] = 1.f / (1.f + __expf(-z));
}

// ---------------- K6: SE excite conv + BN + fp32 store (NCHW) ----------------
__global__ __launch_bounds__(256) void se_out_kernel(
    const float* __restrict__ s_ws, const float* __restrict__ g_ws,
    const float* __restrict__ se_Wout,
    const float* __restrict__ gout, const float* __restrict__ bout,
    const float* __restrict__ mout, const float* __restrict__ vout,
    float* __restrict__ out)
{
    int b = blockIdx.z;
    int o0 = blockIdx.y * 4;
    int p0 = blockIdx.x * 64;
    __shared__ float st[64][17];
    __shared__ float wg[4][16];
    int t = threadIdx.x;
#pragma unroll
    for (int i = 0; i < 4; i++) {
        int idx = i * 256 + t;
        st[idx >> 4][idx & 15] = s_ws[(size_t)(b * HW + p0 + (idx >> 4)) * 16 + (idx & 15)];
    }
    if (t < 64) {
        int ol = t >> 4, j = t & 15;
        wg[ol][j] = se_Wout[(o0 + ol) * 16 + j] * g_ws[b * 16 + j];
    }
    __syncthreads();
    int ol = t >> 6, pl = t & 63;
    float dot = 0.f;
#pragma unroll
    for (int j = 0; j < 16; j++) dot += st[pl][j] * wg[ol][j];
    int o = o0 + ol;
    float sc = gout[o] * rsqrtf(vout[o] + 1e-5f);
    float r = (dot - mout[o]) * sc + bout[o];
    out[((size_t)(b * 256 + o)) * HW + p0 + pl] = r;
}

extern "C" void kernel_launch(void* const* d_in, const int* in_sizes, int n_in,
                              void* d_out, int out_size, void* d_ws, size_t ws_size,
                              hipStream_t stream) {
    const float* x     = (const float*)d_in[0];
    const float* Wq    = (const float*)d_in[1];
    const float* Wk    = (const float*)d_in[2];
    const float* Wv    = (const float*)d_in[3];
    const float* rel_h = (const float*)d_in[4];
    const float* rel_w = (const float*)d_in[5];
    const float* agg_g1 = (const float*)d_in[6];
    const float* agg_b1 = (const float*)d_in[7];
    const float* agg_m1 = (const float*)d_in[8];
    const float* agg_v1 = (const float*)d_in[9];
    const float* agg_W  = (const float*)d_in[10];
    const float* agg_g2 = (const float*)d_in[11];
    const float* agg_b2 = (const float*)d_in[12];
    const float* agg_m2 = (const float*)d_in[13];
    const float* agg_v2 = (const float*)d_in[14];
    const float* se_Win = (const float*)d_in[15];
    const float* se_g_in = (const float*)d_in[16];
    const float* se_b_in = (const float*)d_in[17];
    const float* se_m_in = (const float*)d_in[18];
    const float* se_v_in = (const float*)d_in[19];
    const float* se_fc1  = (const float*)d_in[20];
    const float* se_fc2  = (const float*)d_in[21];
    const float* se_Wout = (const float*)d_in[22];
    const float* se_g_out = (const float*)d_in[23];
    const float* se_b_out = (const float*)d_in[24];
    const float* se_m_out = (const float*)d_in[25];
    const float* se_v_out = (const float*)d_in[26];

    float* ws = (float*)d_ws;
    const size_t NQ = (size_t)BB * HW * CC;   // 3,211,264
    float* q_ws = ws;
    float* k_ws = q_ws + NQ;
    float* v_ws = k_ws + NQ;
    float* ao_ws = v_ws + NQ;
    float* y2_ws = q_ws;                              // alias: q dead after attn
    unsigned short* xt = (unsigned short*)ao_ws;      // alias: xt dead before ao born
    float* s_ws = ao_ws + NQ;
    float* psum = s_ws + (size_t)BB * HW * 16;
    float* g_ws = psum + 64;
    unsigned short* wbf = (unsigned short*)(g_ws + 64);  // 4 x 65536 bf16

    xt_cvt<<<dim3(49, 4, 4), 256, 0, stream>>>(x, xt);
    wcvt<<<dim3(64, 4), 256, 0, stream>>>(Wq, Wk, Wv, agg_W, wbf);
    qkv_mfma<<<dim3(98, 2, 3), 256, 0, stream>>>(xt, wbf, q_ws, k_ws, v_ws);
    attn_kernel<<<dim3(98, 2, 4), 256, 0, stream>>>(q_ws, k_ws, v_ws, rel_h, rel_w, ao_ws);
    agg_mfma<<<dim3(98, 2), 256, 0, stream>>>(ao_ws, wbf + 3 * 65536,
        agg_g1, agg_b1, agg_m1, agg_v1, agg_g2, agg_b2, agg_m2, agg_v2, y2_ws);
    zero64<<<1, 64, 0, stream>>>(psum);
    se_in_kernel<<<dim3(196, 4), 256, 0, stream>>>(y2_ws, se_Win,
        se_g_in, se_b_in, se_m_in, se_v_in, s_ws, psum);
    se_gate<<<1, 64, 0, stream>>>(psum, se_fc1, se_fc2, g_ws);
    se_out_kernel<<<dim3(49, 64, 4), 256, 0, stream>>>(s_ws, g_ws, se_Wout,
        se_g_out, se_b_out, se_m_out, se_v_out, (float*)d_out);
}

// Round 7
// 206.601 us; speedup vs baseline: 2.3902x; 1.0320x over previous
//
#include <hip/hip_runtime.h>
#include <hip/hip_bf16.h>

#define HW 3136
#define HH 56
#define WW 56
#define BB 4
#define CC 256
#define HD 128

// attention tile geometry
#define TH 4
#define TW 8
#define WR 8    // TH+4
#define WC 12   // TW+4
#define WPX 96  // WR*WC
#define KSTR 132  // floats per window pixel in LDS (pad 128->132)
#define SSTR 33   // score buffer stride

// MFMA GEMM geometry: 128x128 tile, BK=64, LDS row = 64 bf16 + pad -> 72 (144 B)
#define ASTR 72

typedef __attribute__((ext_vector_type(8))) short bf16x8;
typedef __attribute__((ext_vector_type(4))) float f32x4;

__device__ __forceinline__ unsigned short f2bf(float f) {
    unsigned int u; __builtin_memcpy(&u, &f, 4);
    unsigned int r = u + 0x7FFFu + ((u >> 16) & 1u);   // RNE
    return (unsigned short)(r >> 16);
}
__device__ __forceinline__ float bflo(unsigned int u) {
    unsigned int x = u << 16; float f; __builtin_memcpy(&f, &x, 4); return f;
}
__device__ __forceinline__ float bfhi(unsigned int u) {
    unsigned int x = u & 0xFFFF0000u; float f; __builtin_memcpy(&f, &x, 4); return f;
}

// ---------------- K0a: x [b][c][p] fp32 -> xt [(b*HW+p)][c] bf16 -------------
__global__ __launch_bounds__(256) void xt_cvt(const float* __restrict__ x,
                                              unsigned short* __restrict__ xt)
{
    int b = blockIdx.z;
    int c0 = blockIdx.y * 64;
    int p0 = blockIdx.x * 64;
    __shared__ float tile[64][65];   // [channel][pixel]
    int t = threadIdx.x;
    int p4 = t & 15, cl = t >> 4;
    const float* xb = x + ((size_t)b * CC + c0) * HW + p0;
#pragma unroll
    for (int i = 0; i < 4; i++) {
        int c = cl + 16 * i;
        float4 f = *(const float4*)(xb + (size_t)c * HW + p4 * 4);
        tile[c][p4 * 4 + 0] = f.x; tile[c][p4 * 4 + 1] = f.y;
        tile[c][p4 * 4 + 2] = f.z; tile[c][p4 * 4 + 3] = f.w;
    }
    __syncthreads();
    int c2 = t & 31, pl = t >> 5;
    unsigned short* xo = xt + ((size_t)b * HW + p0) * CC + c0;
#pragma unroll
    for (int i = 0; i < 8; i++) {
        int p = pl + 8 * i;
        float a = tile[2 * c2][p], bb = tile[2 * c2 + 1][p];
        unsigned int pk = (unsigned int)f2bf(a) | ((unsigned int)f2bf(bb) << 16);
        *(unsigned int*)(xo + (size_t)p * CC + 2 * c2) = pk;
    }
}

// ---------------- K0b: weights fp32 -> bf16 (Wq,Wk,Wv,aggW) ------------------
__global__ __launch_bounds__(256) void wcvt(const float* __restrict__ Wq,
                                            const float* __restrict__ Wk,
                                            const float* __restrict__ Wv,
                                            const float* __restrict__ Wa,
                                            unsigned short* __restrict__ wb)
{
    const float* srcs[4] = {Wq, Wk, Wv, Wa};
    const float* s = srcs[blockIdx.y];
    int idx = blockIdx.x * 256 + threadIdx.x;       // 0..16383
    float4 f = *(const float4*)(s + (size_t)idx * 4);
    uint2 pk;
    pk.x = (unsigned int)f2bf(f.x) | ((unsigned int)f2bf(f.y) << 16);
    pk.y = (unsigned int)f2bf(f.z) | ((unsigned int)f2bf(f.w) << 16);
    *(uint2*)(wb + (size_t)blockIdx.y * 65536 + (size_t)idx * 4) = pk;
}

// ---------------- K1: qkv via MFMA bf16, outputs bf16 [(b*HW+p)][o] ----------
// grid: (98, 2, 3)
__global__ __launch_bounds__(256) void qkv_mfma(
    const unsigned short* __restrict__ xt, const unsigned short* __restrict__ wqkv,
    unsigned short* __restrict__ q_ws, unsigned short* __restrict__ k_ws,
    unsigned short* __restrict__ v_ws)
{
    int wsel = blockIdx.z;
    unsigned short* outp = (wsel == 0) ? q_ws : ((wsel == 1) ? k_ws : v_ws);
    int gp0 = blockIdx.x * 128, o0 = blockIdx.y * 128;

    __shared__ unsigned short As[128 * ASTR];
    __shared__ unsigned short Bs[128 * ASTR];
    const unsigned short* xb = xt + (size_t)gp0 * CC;
    const unsigned short* wbp = wqkv + (size_t)wsel * 65536 + (size_t)o0 * CC;

    int t = threadIdx.x;
    int wave = t >> 6, lane = t & 63;
    int mo = (wave & 1) * 64, no = (wave >> 1) * 64;
    int lm = lane & 15, lq = lane >> 4;
    int sr = t >> 3, sc = t & 7;

    f32x4 acc[4][4];
#pragma unroll
    for (int i = 0; i < 4; i++)
#pragma unroll
        for (int j = 0; j < 4; j++) acc[i][j] = (f32x4){0.f, 0.f, 0.f, 0.f};

    for (int k0 = 0; k0 < 256; k0 += 64) {
#pragma unroll
        for (int i = 0; i < 4; i++) {
            int r = sr + 32 * i;
            *(uint4*)&As[r * ASTR + sc * 8] = *(const uint4*)(xb + (size_t)r * CC + k0 + sc * 8);
            *(uint4*)&Bs[r * ASTR + sc * 8] = *(const uint4*)(wbp + (size_t)r * CC + k0 + sc * 8);
        }
        __syncthreads();
#pragma unroll
        for (int ks = 0; ks < 64; ks += 32) {
            bf16x8 af[4], bfr[4];
#pragma unroll
            for (int i = 0; i < 4; i++)
                af[i] = *(bf16x8*)&As[(mo + 16 * i + lm) * ASTR + ks + lq * 8];
#pragma unroll
            for (int j = 0; j < 4; j++)
                bfr[j] = *(bf16x8*)&Bs[(no + 16 * j + lm) * ASTR + ks + lq * 8];
#pragma unroll
            for (int i = 0; i < 4; i++)
#pragma unroll
                for (int j = 0; j < 4; j++)
                    acc[i][j] = __builtin_amdgcn_mfma_f32_16x16x32_bf16(
                        af[i], bfr[j], acc[i][j], 0, 0, 0);
        }
        __syncthreads();
    }
    // epilogue: pack adjacent-column pairs via shfl, write bf16
    unsigned short* ob = outp + (size_t)gp0 * CC + o0;
    bool ev = (lm & 1) == 0;
    int elm = lm & ~1;
#pragma unroll
    for (int i = 0; i < 4; i++)
#pragma unroll
        for (int j = 0; j < 4; j++)
#pragma unroll
            for (int r = 0; r < 4; r++) {
                float v = acc[i][j][r];
                float p = __shfl_xor(v, 1, 64);
                unsigned int pk = ev
                    ? ((unsigned int)f2bf(v) | ((unsigned int)f2bf(p) << 16))
                    : ((unsigned int)f2bf(p) | ((unsigned int)f2bf(v) << 16));
                if (ev == (r < 2)) {   // even lanes: rows 0,1; odd lanes: rows 2,3
                    int m = mo + 16 * i + lq * 4 + r;
                    int n = no + 16 * j + elm;
                    *(unsigned int*)(ob + (size_t)m * CC + n) = pk;
                }
            }
}

// ---------------- K3: agg via MFMA bf16 (ao bf16 in); BN1+ReLU / BN2 fused ---
// grid: (98, 2)
__global__ __launch_bounds__(256) void agg_mfma(
    const unsigned short* __restrict__ ao, const unsigned short* __restrict__ wagg,
    const float* __restrict__ g1, const float* __restrict__ b1,
    const float* __restrict__ m1, const float* __restrict__ v1,
    const float* __restrict__ g2, const float* __restrict__ b2,
    const float* __restrict__ m2, const float* __restrict__ v2,
    float* __restrict__ y2)
{
    int gp0 = blockIdx.x * 128, o0 = blockIdx.y * 128;

    __shared__ unsigned short As[128 * ASTR];
    __shared__ unsigned short Bs[128 * ASTR];
    __shared__ float s1[256], o1[256], s2[256], o2[256];

    int t = threadIdx.x;
    {
        float sc1 = g1[t] * rsqrtf(v1[t] + 1e-5f);
        s1[t] = sc1; o1[t] = b1[t] - m1[t] * sc1;
        float sc2 = g2[t] * rsqrtf(v2[t] + 1e-5f);
        s2[t] = sc2; o2[t] = b2[t] - m2[t] * sc2;
    }

    const unsigned short* aob = ao + (size_t)gp0 * CC;
    const unsigned short* wbp = wagg + (size_t)o0 * CC;

    int wave = t >> 6, lane = t & 63;
    int mo = (wave & 1) * 64, no = (wave >> 1) * 64;
    int lm = lane & 15, lq = lane >> 4;
    int sr = t >> 3, sc = t & 7;

    f32x4 acc[4][4];
#pragma unroll
    for (int i = 0; i < 4; i++)
#pragma unroll
        for (int j = 0; j < 4; j++) acc[i][j] = (f32x4){0.f, 0.f, 0.f, 0.f};

    __syncthreads();   // s1/o1 ready before first use

    for (int k0 = 0; k0 < 256; k0 += 64) {
#pragma unroll
        for (int i = 0; i < 4; i++) {
            int r = sr + 32 * i;
            int cb = k0 + sc * 8;
            uint4 u = *(const uint4*)(aob + (size_t)r * CC + cb);
            float e[8] = {bflo(u.x), bfhi(u.x), bflo(u.y), bfhi(u.y),
                          bflo(u.z), bfhi(u.z), bflo(u.w), bfhi(u.w)};
            unsigned short pk[8];
#pragma unroll
            for (int uu = 0; uu < 8; uu++) {
                float vv = fmaxf(e[uu] * s1[cb + uu] + o1[cb + uu], 0.f);
                pk[uu] = f2bf(vv);
            }
            *(uint4*)&As[r * ASTR + sc * 8] = *(uint4*)pk;
            *(uint4*)&Bs[r * ASTR + sc * 8] = *(const uint4*)(wbp + (size_t)r * CC + k0 + sc * 8);
        }
        __syncthreads();
#pragma unroll
        for (int ks = 0; ks < 64; ks += 32) {
            bf16x8 af[4], bfr[4];
#pragma unroll
            for (int i = 0; i < 4; i++)
                af[i] = *(bf16x8*)&As[(mo + 16 * i + lm) * ASTR + ks + lq * 8];
#pragma unroll
            for (int j = 0; j < 4; j++)
                bfr[j] = *(bf16x8*)&Bs[(no + 16 * j + lm) * ASTR + ks + lq * 8];
#pragma unroll
            for (int i = 0; i < 4; i++)
#pragma unroll
                for (int j = 0; j < 4; j++)
                    acc[i][j] = __builtin_amdgcn_mfma_f32_16x16x32_bf16(
                        af[i], bfr[j], acc[i][j], 0, 0, 0);
        }
        __syncthreads();
    }
    float* yb = y2 + (size_t)gp0 * CC + o0;
#pragma unroll
    for (int i = 0; i < 4; i++)
#pragma unroll
        for (int j = 0; j < 4; j++)
#pragma unroll
            for (int r = 0; r < 4; r++) {
                int m = mo + 16 * i + lq * 4 + r;
                int n = no + 16 * j + lm;
                yb[(size_t)m * CC + n] = acc[i][j][r] * s2[o0 + n] + o2[o0 + n];
            }
}

// ---------------- K2: local attention (bf16 q/k/v/ao), LDS-tiled -------------
__global__ __launch_bounds__(256) void attn_kernel(
    const unsigned short* __restrict__ q_ws, const unsigned short* __restrict__ k_ws,
    const unsigned short* __restrict__ v_ws,
    const float* __restrict__ rel_h, const float* __restrict__ rel_w,
    unsigned short* __restrict__ ao_ws)
{
    __shared__ float kwin[WPX * KSTR];   // fp32 in LDS; holds k, then v
    __shared__ float sbuf[32 * SSTR];
    __shared__ float relT[5 * KSTR];

    int t = threadIdx.x;
    int tile = blockIdx.x;
    int n = blockIdx.y;
    int b = blockIdx.z;
    int tr = tile / 7, tc = tile - tr * 7;
    int h0 = tr * TH, w0 = tc * TW;
    const float* rel = (n == 0) ? rel_h : rel_w;
    const size_t base = (size_t)b * HW * CC + n * HD;

    {   // stage k window: 16 ch-chunks (8 ch) x 16 wpx per pass, 6 passes
        int c8 = t & 15, pw0 = t >> 4;
#pragma unroll
        for (int it = 0; it < 6; it++) {
            int pw = pw0 + it * 16;
            int wr = pw / 12, wc = pw - wr * 12;
            int gh = h0 + wr - 2, gw = w0 + wc - 2;
            float f[8] = {0.f, 0.f, 0.f, 0.f, 0.f, 0.f, 0.f, 0.f};
            if (gh >= 0 && gh < HH && gw >= 0 && gw < WW) {
                uint4 u = *(const uint4*)(k_ws + base + (size_t)(gh * WW + gw) * CC + c8 * 8);
                f[0] = bflo(u.x); f[1] = bfhi(u.x); f[2] = bflo(u.y); f[3] = bfhi(u.y);
                f[4] = bflo(u.z); f[5] = bfhi(u.z); f[6] = bflo(u.w); f[7] = bfhi(u.w);
            }
            *(float4*)&kwin[pw * KSTR + c8 * 8]     = make_float4(f[0], f[1], f[2], f[3]);
            *(float4*)&kwin[pw * KSTR + c8 * 8 + 4] = make_float4(f[4], f[5], f[6], f[7]);
        }
        if (t < 128) {
#pragma unroll
            for (int tt = 0; tt < 5; tt++)
                relT[tt * KSTR + t] = rel[t * 5 + tt];
        }
    }
    __syncthreads();

    int px = t >> 3, c4g = t & 7;
    int pr = px >> 3, pc = px & 7;
    int ghp = h0 + pr, gwp = w0 + pc;
    const size_t pbase = base + (size_t)(ghp * WW + gwp) * CC;

    float4 q4[4];
#pragma unroll
    for (int i = 0; i < 4; i++) {
        uint2 uq = *(const uint2*)(q_ws + pbase + (c4g + 8 * i) * 4);
        q4[i] = make_float4(bflo(uq.x), bfhi(uq.x), bflo(uq.y), bfhi(uq.y));
    }

    float acc[30];
#pragma unroll
    for (int tt = 0; tt < 30; tt++) acc[tt] = 0.f;
#pragma unroll
    for (int i = 0; i < 4; i++) {
        float4 q = q4[i];
        int co = (c4g + 8 * i) * 4;
#pragma unroll
        for (int tt = 0; tt < 25; tt++) {
            int di = tt / 5, dj = tt - 5 * (tt / 5);
            int wpx = (pr + di) * WC + pc + dj;
            float4 k4 = *(const float4*)&kwin[wpx * KSTR + co];
            acc[tt] += q.x * k4.x + q.y * k4.y + q.z * k4.z + q.w * k4.w;
        }
#pragma unroll
        for (int tt = 0; tt < 5; tt++) {
            float4 r4 = *(const float4*)&relT[tt * KSTR + co];
            acc[25 + tt] += q.x * r4.x + q.y * r4.y + q.z * r4.z + q.w * r4.w;
        }
    }
#pragma unroll
    for (int tt = 0; tt < 30; tt++) {
#pragma unroll
        for (int m = 1; m < 8; m <<= 1)
            acc[tt] += __shfl_xor(acc[tt], m, 64);
    }
#pragma unroll
    for (int tt = 0; tt < 30; tt++)
        if ((tt & 7) == c4g) sbuf[px * SSTR + tt] = acc[tt];
    __syncthreads();

    {   // stage v into same buffer
        int c8 = t & 15, pw0 = t >> 4;
#pragma unroll
        for (int it = 0; it < 6; it++) {
            int pw = pw0 + it * 16;
            int wr = pw / 12, wc = pw - wr * 12;
            int gh = h0 + wr - 2, gw = w0 + wc - 2;
            float f[8] = {0.f, 0.f, 0.f, 0.f, 0.f, 0.f, 0.f, 0.f};
            if (gh >= 0 && gh < HH && gw >= 0 && gw < WW) {
                uint4 u = *(const uint4*)(v_ws + base + (size_t)(gh * WW + gw) * CC + c8 * 8);
                f[0] = bflo(u.x); f[1] = bfhi(u.x); f[2] = bflo(u.y); f[3] = bfhi(u.y);
                f[4] = bflo(u.z); f[5] = bfhi(u.z); f[6] = bflo(u.w); f[7] = bfhi(u.w);
            }
            *(float4*)&kwin[pw * KSTR + c8 * 8]     = make_float4(f[0], f[1], f[2], f[3]);
            *(float4*)&kwin[pw * KSTR + c8 * 8 + 4] = make_float4(f[4], f[5], f[6], f[7]);
        }
    }
    if (t < 32) {
        float s[25], b5[5];
#pragma unroll
        for (int tt = 0; tt < 25; tt++) s[tt] = sbuf[t * SSTR + tt];
#pragma unroll
        for (int tt = 0; tt < 5; tt++) b5[tt] = sbuf[t * SSTR + 25 + tt];
        const float inv = 0.08838834764831845f;
        float mx = -1e30f;
#pragma unroll
        for (int tt = 0; tt < 25; tt++) {
            int di = tt / 5, dj = tt - 5 * (tt / 5);
            s[tt] = (s[tt] + ((n == 0) ? b5[di] : b5[dj])) * inv;
            mx = fmaxf(mx, s[tt]);
        }
        float sum = 0.f;
#pragma unroll
        for (int tt = 0; tt < 25; tt++) { s[tt] = __expf(s[tt] - mx); sum += s[tt]; }
        float rs = 1.f / sum;
#pragma unroll
        for (int tt = 0; tt < 25; tt++) sbuf[t * SSTR + tt] = s[tt] * rs;
    }
    __syncthreads();

    float w25[25];
#pragma unroll
    for (int tt = 0; tt < 25; tt++) w25[tt] = sbuf[px * SSTR + tt];
    float4 oacc[4];
#pragma unroll
    for (int i = 0; i < 4; i++) oacc[i] = make_float4(0.f, 0.f, 0.f, 0.f);
#pragma unroll
    for (int tt = 0; tt < 25; tt++) {
        int di = tt / 5, dj = tt - 5 * (tt / 5);
        int wpx = (pr + di) * WC + pc + dj;
        float a = w25[tt];
#pragma unroll
        for (int i = 0; i < 4; i++) {
            float4 v4 = *(const float4*)&kwin[wpx * KSTR + (c4g + 8 * i) * 4];
            oacc[i].x += a * v4.x; oacc[i].y += a * v4.y;
            oacc[i].z += a * v4.z; oacc[i].w += a * v4.w;
        }
    }
#pragma unroll
    for (int i = 0; i < 4; i++) {
        uint2 pk;
        pk.x = (unsigned int)f2bf(oacc[i].x) | ((unsigned int)f2bf(oacc[i].y) << 16);
        pk.y = (unsigned int)f2bf(oacc[i].z) | ((unsigned int)f2bf(oacc[i].w) << 16);
        *(uint2*)(ao_ws + pbase + (c4g + 8 * i) * 4) = pk;
    }
}

// ---------------- K4: SE squeeze conv + partial mean -------------------------
__global__ __launch_bounds__(256) void se_in_kernel(
    const float* __restrict__ y2, const float* __restrict__ se_Win,
    const float* __restrict__ gin, const float* __restrict__ bin,
    const float* __restrict__ min_, const float* __restrict__ vin,
    float* __restrict__ s_ws, float* __restrict__ psum)
{
    int b = blockIdx.y;
    int p0 = blockIdx.x * 16;
    __shared__ float yt[16][257];
    __shared__ float wt[16][257];
    __shared__ float red[16][17];
    int t = threadIdx.x;
    const float* yb = y2 + (size_t)(b * HW + p0) * CC;
#pragma unroll
    for (int i = 0; i < 16; i++) yt[i][t] = yb[(size_t)i * CC + t];
#pragma unroll
    for (int i = 0; i < 16; i++) wt[i][t] = se_Win[i * 256 + t];
    __syncthreads();
    int p = t >> 4, j = t & 15;
    float dot = 0.f;
#pragma unroll 8
    for (int c = 0; c < 256; c++) dot += yt[p][c] * wt[j][c];
    float sc = gin[j] * rsqrtf(vin[j] + 1e-5f);
    float sv = fmaxf((dot - min_[j]) * sc + bin[j], 0.f);
    s_ws[(size_t)(b * HW + p0 + p) * 16 + j] = sv;
    red[p][j] = sv;
    __syncthreads();
    if (t < 16) {
        float sm = 0.f;
#pragma unroll
        for (int pp = 0; pp < 16; pp++) sm += red[pp][t];
        atomicAdd(&psum[b * 16 + t], sm);
    }
}

__global__ void zero64(float* p) { p[threadIdx.x] = 0.f; }

// ---------------- K5: SE gate ------------------------------------------------
__global__ void se_gate(const float* __restrict__ psum,
                        const float* __restrict__ fc1,
                        const float* __restrict__ fc2,
                        float* __restrict__ g_ws)
{
    int t = threadIdx.x;
    if (t >= 64) return;
    int b = t >> 4, j = t & 15;
    float h = 0.f;
#pragma unroll
    for (int jj = 0; jj < 16; jj++)
        h += (psum[b * 16 + jj] * (1.f / 3136.f)) * fc1[jj];
    h = fmaxf(h, 0.f);
    float z = h * fc2[j];
    g_ws[t] = 1.f / (1.f + __expf(-z));
}

// ---------------- K6: SE excite conv + BN + fp32 store (NCHW) ----------------
__global__ __launch_bounds__(256) void se_out_kernel(
    const float* __restrict__ s_ws, const float* __restrict__ g_ws,
    const float* __restrict__ se_Wout,
    const float* __restrict__ gout, const float* __restrict__ bout,
    const float* __restrict__ mout, const float* __restrict__ vout,
    float* __restrict__ out)
{
    int b = blockIdx.z;
    int o0 = blockIdx.y * 4;
    int p0 = blockIdx.x * 64;
    __shared__ float st[64][17];
    __shared__ float wg[4][16];
    int t = threadIdx.x;
#pragma unroll
    for (int i = 0; i < 4; i++) {
        int idx = i * 256 + t;
        st[idx >> 4][idx & 15] = s_ws[(size_t)(b * HW + p0 + (idx >> 4)) * 16 + (idx & 15)];
    }
    if (t < 64) {
        int ol = t >> 4, j = t & 15;
        wg[ol][j] = se_Wout[(o0 + ol) * 16 + j] * g_ws[b * 16 + j];
    }
    __syncthreads();
    int ol = t >> 6, pl = t & 63;
    float dot = 0.f;
#pragma unroll
    for (int j = 0; j < 16; j++) dot += st[pl][j] * wg[ol][j];
    int o = o0 + ol;
    float sc = gout[o] * rsqrtf(vout[o] + 1e-5f);
    float r = (dot - mout[o]) * sc + bout[o];
    out[((size_t)(b * 256 + o)) * HW + p0 + pl] = r;
}

extern "C" void kernel_launch(void* const* d_in, const int* in_sizes, int n_in,
                              void* d_out, int out_size, void* d_ws, size_t ws_size,
                              hipStream_t stream) {
    const float* x     = (const float*)d_in[0];
    const float* Wq    = (const float*)d_in[1];
    const float* Wk    = (const float*)d_in[2];
    const float* Wv    = (const float*)d_in[3];
    const float* rel_h = (const float*)d_in[4];
    const float* rel_w = (const float*)d_in[5];
    const float* agg_g1 = (const float*)d_in[6];
    const float* agg_b1 = (const float*)d_in[7];
    const float* agg_m1 = (const float*)d_in[8];
    const float* agg_v1 = (const float*)d_in[9];
    const float* agg_W  = (const float*)d_in[10];
    const float* agg_g2 = (const float*)d_in[11];
    const float* agg_b2 = (const float*)d_in[12];
    const float* agg_m2 = (const float*)d_in[13];
    const float* agg_v2 = (const float*)d_in[14];
    const float* se_Win = (const float*)d_in[15];
    const float* se_g_in = (const float*)d_in[16];
    const float* se_b_in = (const float*)d_in[17];
    const float* se_m_in = (const float*)d_in[18];
    const float* se_v_in = (const float*)d_in[19];
    const float* se_fc1  = (const float*)d_in[20];
    const float* se_fc2  = (const float*)d_in[21];
    const float* se_Wout = (const float*)d_in[22];
    const float* se_g_out = (const float*)d_in[23];
    const float* se_b_out = (const float*)d_in[24];
    const float* se_m_out = (const float*)d_in[25];
    const float* se_v_out = (const float*)d_in[26];

    const size_t NQ = (size_t)BB * HW * CC;   // 3,211,264
    unsigned short* q_ws  = (unsigned short*)d_ws;   // bf16, NQ each
    unsigned short* k_ws  = q_ws + NQ;
    unsigned short* v_ws  = k_ws + NQ;
    unsigned short* ao_ws = v_ws + NQ;
    unsigned short* xt    = ao_ws;                   // alias: xt dead before ao born
    float* y2_ws = (float*)d_ws;                     // alias over q+k (4*NQ bytes exactly)
    float* s_ws  = (float*)(ao_ws + NQ);
    float* psum  = s_ws + (size_t)BB * HW * 16;
    float* g_ws  = psum + 64;
    unsigned short* wbf = (unsigned short*)(g_ws + 64);  // 4 x 65536 bf16

    xt_cvt<<<dim3(49, 4, 4), 256, 0, stream>>>(x, xt);
    wcvt<<<dim3(64, 4), 256, 0, stream>>>(Wq, Wk, Wv, agg_W, wbf);
    qkv_mfma<<<dim3(98, 2, 3), 256, 0, stream>>>(xt, wbf, q_ws, k_ws, v_ws);
    attn_kernel<<<dim3(98, 2, 4), 256, 0, stream>>>(q_ws, k_ws, v_ws, rel_h, rel_w, ao_ws);
    agg_mfma<<<dim3(98, 2), 256, 0, stream>>>(ao_ws, wbf + 3 * 65536,
        agg_g1, agg_b1, agg_m1, agg_v1, agg_g2, agg_b2, agg_m2, agg_v2, y2_ws);
    zero64<<<1, 64, 0, stream>>>(psum);
    se_in_kernel<<<dim3(196, 4), 256, 0, stream>>>(y2_ws, se_Win,
        se_g_in, se_b_in, se_m_in, se_v_in, s_ws, psum);
    se_gate<<<1, 64, 0, stream>>>(psum, se_fc1, se_fc2, g_ws);
    se_out_kernel<<<dim3(49, 64, 4), 256, 0, stream>>>(s_ws, g_ws, se_Wout,
        se_g_out, se_b_out, se_m_out, se_v_out, (float*)d_out);
}

// Round 8
// 196.990 us; speedup vs baseline: 2.5069x; 1.0488x over previous
//
#include <hip/hip_runtime.h>
#include <hip/hip_bf16.h>

#define HW 3136
#define HH 56
#define WW 56
#define BB 4
#define CC 256
#define HD 128

// attention tile geometry
#define TH 4
#define TW 8
#define WR 8    // TH+4
#define WC 12   // TW+4
#define WPX 96  // WR*WC
#define KSTR 132  // floats per window pixel in LDS (pad 128->132)

// MFMA GEMM geometry: 128x128 tile, BK=64, LDS row = 64 bf16 + pad -> 72 (144 B)
#define ASTR 72

typedef __attribute__((ext_vector_type(8))) short bf16x8;
typedef __attribute__((ext_vector_type(4))) float f32x4;

__device__ __forceinline__ unsigned short f2bf(float f) {
    unsigned int u; __builtin_memcpy(&u, &f, 4);
    unsigned int r = u + 0x7FFFu + ((u >> 16) & 1u);   // RNE
    return (unsigned short)(r >> 16);
}
__device__ __forceinline__ float bflo(unsigned int u) {
    unsigned int x = u << 16; float f; __builtin_memcpy(&f, &x, 4); return f;
}
__device__ __forceinline__ float bfhi(unsigned int u) {
    unsigned int x = u & 0xFFFF0000u; float f; __builtin_memcpy(&f, &x, 4); return f;
}

// ---------------- K0a: x [b][c][p] fp32 -> xt [(b*HW+p)][c] bf16 -------------
__global__ __launch_bounds__(256) void xt_cvt(const float* __restrict__ x,
                                              unsigned short* __restrict__ xt)
{
    int b = blockIdx.z;
    int c0 = blockIdx.y * 64;
    int p0 = blockIdx.x * 64;
    __shared__ float tile[64][65];   // [channel][pixel]
    int t = threadIdx.x;
    int p4 = t & 15, cl = t >> 4;
    const float* xb = x + ((size_t)b * CC + c0) * HW + p0;
#pragma unroll
    for (int i = 0; i < 4; i++) {
        int c = cl + 16 * i;
        float4 f = *(const float4*)(xb + (size_t)c * HW + p4 * 4);
        tile[c][p4 * 4 + 0] = f.x; tile[c][p4 * 4 + 1] = f.y;
        tile[c][p4 * 4 + 2] = f.z; tile[c][p4 * 4 + 3] = f.w;
    }
    __syncthreads();
    int c2 = t & 31, pl = t >> 5;
    unsigned short* xo = xt + ((size_t)b * HW + p0) * CC + c0;
#pragma unroll
    for (int i = 0; i < 8; i++) {
        int p = pl + 8 * i;
        float a = tile[2 * c2][p], bb = tile[2 * c2 + 1][p];
        unsigned int pk = (unsigned int)f2bf(a) | ((unsigned int)f2bf(bb) << 16);
        *(unsigned int*)(xo + (size_t)p * CC + 2 * c2) = pk;
    }
}

// ---------------- K0b: weights fp32 -> bf16 + psum zero ----------------------
// grid (64,5): y<4 -> Wq/Wk/Wv/Wa (65536 each); y==4 -> se_Win (4096) + psum=0
__global__ __launch_bounds__(256) void wcvt(const float* __restrict__ Wq,
                                            const float* __restrict__ Wk,
                                            const float* __restrict__ Wv,
                                            const float* __restrict__ Wa,
                                            const float* __restrict__ Wse,
                                            unsigned short* __restrict__ wb,
                                            float* __restrict__ psum)
{
    int t = threadIdx.x;
    if (blockIdx.y == 4) {
        if (blockIdx.x == 0 && t < 64) psum[t] = 0.f;
        int idx = blockIdx.x * 256 + t;
        if (idx < 1024) {
            float4 f = *(const float4*)(Wse + (size_t)idx * 4);
            uint2 pk;
            pk.x = (unsigned int)f2bf(f.x) | ((unsigned int)f2bf(f.y) << 16);
            pk.y = (unsigned int)f2bf(f.z) | ((unsigned int)f2bf(f.w) << 16);
            *(uint2*)(wb + (size_t)4 * 65536 + (size_t)idx * 4) = pk;
        }
        return;
    }
    const float* srcs[4] = {Wq, Wk, Wv, Wa};
    const float* s = srcs[blockIdx.y];
    int idx = blockIdx.x * 256 + t;
    float4 f = *(const float4*)(s + (size_t)idx * 4);
    uint2 pk;
    pk.x = (unsigned int)f2bf(f.x) | ((unsigned int)f2bf(f.y) << 16);
    pk.y = (unsigned int)f2bf(f.z) | ((unsigned int)f2bf(f.w) << 16);
    *(uint2*)(wb + (size_t)blockIdx.y * 65536 + (size_t)idx * 4) = pk;
}

// ---------------- K1: qkv via MFMA bf16, outputs bf16 [(b*HW+p)][o] ----------
__global__ __launch_bounds__(256) void qkv_mfma(
    const unsigned short* __restrict__ xt, const unsigned short* __restrict__ wqkv,
    unsigned short* __restrict__ q_ws, unsigned short* __restrict__ k_ws,
    unsigned short* __restrict__ v_ws)
{
    int wsel = blockIdx.z;
    unsigned short* outp = (wsel == 0) ? q_ws : ((wsel == 1) ? k_ws : v_ws);
    int gp0 = blockIdx.x * 128, o0 = blockIdx.y * 128;

    __shared__ unsigned short As[128 * ASTR];
    __shared__ unsigned short Bs[128 * ASTR];
    const unsigned short* xb = xt + (size_t)gp0 * CC;
    const unsigned short* wbp = wqkv + (size_t)wsel * 65536 + (size_t)o0 * CC;

    int t = threadIdx.x;
    int wave = t >> 6, lane = t & 63;
    int mo = (wave & 1) * 64, no = (wave >> 1) * 64;
    int lm = lane & 15, lq = lane >> 4;
    int sr = t >> 3, sc = t & 7;

    f32x4 acc[4][4];
#pragma unroll
    for (int i = 0; i < 4; i++)
#pragma unroll
        for (int j = 0; j < 4; j++) acc[i][j] = (f32x4){0.f, 0.f, 0.f, 0.f};

    for (int k0 = 0; k0 < 256; k0 += 64) {
#pragma unroll
        for (int i = 0; i < 4; i++) {
            int r = sr + 32 * i;
            *(uint4*)&As[r * ASTR + sc * 8] = *(const uint4*)(xb + (size_t)r * CC + k0 + sc * 8);
            *(uint4*)&Bs[r * ASTR + sc * 8] = *(const uint4*)(wbp + (size_t)r * CC + k0 + sc * 8);
        }
        __syncthreads();
#pragma unroll
        for (int ks = 0; ks < 64; ks += 32) {
            bf16x8 af[4], bfr[4];
#pragma unroll
            for (int i = 0; i < 4; i++)
                af[i] = *(bf16x8*)&As[(mo + 16 * i + lm) * ASTR + ks + lq * 8];
#pragma unroll
            for (int j = 0; j < 4; j++)
                bfr[j] = *(bf16x8*)&Bs[(no + 16 * j + lm) * ASTR + ks + lq * 8];
#pragma unroll
            for (int i = 0; i < 4; i++)
#pragma unroll
                for (int j = 0; j < 4; j++)
                    acc[i][j] = __builtin_amdgcn_mfma_f32_16x16x32_bf16(
                        af[i], bfr[j], acc[i][j], 0, 0, 0);
        }
        __syncthreads();
    }
    unsigned short* ob = outp + (size_t)gp0 * CC + o0;
    bool ev = (lm & 1) == 0;
    int elm = lm & ~1;
#pragma unroll
    for (int i = 0; i < 4; i++)
#pragma unroll
        for (int j = 0; j < 4; j++)
#pragma unroll
            for (int r = 0; r < 4; r++) {
                float v = acc[i][j][r];
                float p = __shfl_xor(v, 1, 64);
                unsigned int pk = ev
                    ? ((unsigned int)f2bf(v) | ((unsigned int)f2bf(p) << 16))
                    : ((unsigned int)f2bf(p) | ((unsigned int)f2bf(v) << 16));
                if (ev == (r < 2)) {
                    int m = mo + 16 * i + lq * 4 + r;
                    int n = no + 16 * j + elm;
                    *(unsigned int*)(ob + (size_t)m * CC + n) = pk;
                }
            }
}

// ---------------- K3: agg via MFMA bf16 (ao bf16 in); BN1+ReLU / BN2 fused ---
__global__ __launch_bounds__(256) void agg_mfma(
    const unsigned short* __restrict__ ao, const unsigned short* __restrict__ wagg,
    const float* __restrict__ g1, const float* __restrict__ b1,
    const float* __restrict__ m1, const float* __restrict__ v1,
    const float* __restrict__ g2, const float* __restrict__ b2,
    const float* __restrict__ m2, const float* __restrict__ v2,
    float* __restrict__ y2)
{
    int gp0 = blockIdx.x * 128, o0 = blockIdx.y * 128;

    __shared__ unsigned short As[128 * ASTR];
    __shared__ unsigned short Bs[128 * ASTR];
    __shared__ float s1[256], o1[256], s2[256], o2[256];

    int t = threadIdx.x;
    {
        float sc1 = g1[t] * rsqrtf(v1[t] + 1e-5f);
        s1[t] = sc1; o1[t] = b1[t] - m1[t] * sc1;
        float sc2 = g2[t] * rsqrtf(v2[t] + 1e-5f);
        s2[t] = sc2; o2[t] = b2[t] - m2[t] * sc2;
    }

    const unsigned short* aob = ao + (size_t)gp0 * CC;
    const unsigned short* wbp = wagg + (size_t)o0 * CC;

    int wave = t >> 6, lane = t & 63;
    int mo = (wave & 1) * 64, no = (wave >> 1) * 64;
    int lm = lane & 15, lq = lane >> 4;
    int sr = t >> 3, sc = t & 7;

    f32x4 acc[4][4];
#pragma unroll
    for (int i = 0; i < 4; i++)
#pragma unroll
        for (int j = 0; j < 4; j++) acc[i][j] = (f32x4){0.f, 0.f, 0.f, 0.f};

    __syncthreads();

    for (int k0 = 0; k0 < 256; k0 += 64) {
#pragma unroll
        for (int i = 0; i < 4; i++) {
            int r = sr + 32 * i;
            int cb = k0 + sc * 8;
            uint4 u = *(const uint4*)(aob + (size_t)r * CC + cb);
            float e[8] = {bflo(u.x), bfhi(u.x), bflo(u.y), bfhi(u.y),
                          bflo(u.z), bfhi(u.z), bflo(u.w), bfhi(u.w)};
            unsigned short pk[8];
#pragma unroll
            for (int uu = 0; uu < 8; uu++) {
                float vv = fmaxf(e[uu] * s1[cb + uu] + o1[cb + uu], 0.f);
                pk[uu] = f2bf(vv);
            }
            *(uint4*)&As[r * ASTR + sc * 8] = *(uint4*)pk;
            *(uint4*)&Bs[r * ASTR + sc * 8] = *(const uint4*)(wbp + (size_t)r * CC + k0 + sc * 8);
        }
        __syncthreads();
#pragma unroll
        for (int ks = 0; ks < 64; ks += 32) {
            bf16x8 af[4], bfr[4];
#pragma unroll
            for (int i = 0; i < 4; i++)
                af[i] = *(bf16x8*)&As[(mo + 16 * i + lm) * ASTR + ks + lq * 8];
#pragma unroll
            for (int j = 0; j < 4; j++)
                bfr[j] = *(bf16x8*)&Bs[(no + 16 * j + lm) * ASTR + ks + lq * 8];
#pragma unroll
            for (int i = 0; i < 4; i++)
#pragma unroll
                for (int j = 0; j < 4; j++)
                    acc[i][j] = __builtin_amdgcn_mfma_f32_16x16x32_bf16(
                        af[i], bfr[j], acc[i][j], 0, 0, 0);
        }
        __syncthreads();
    }
    float* yb = y2 + (size_t)gp0 * CC + o0;
#pragma unroll
    for (int i = 0; i < 4; i++)
#pragma unroll
        for (int j = 0; j < 4; j++)
#pragma unroll
            for (int r = 0; r < 4; r++) {
                int m = mo + 16 * i + lq * 4 + r;
                int n = no + 16 * j + lm;
                yb[(size_t)m * CC + n] = acc[i][j][r] * s2[o0 + n] + o2[o0 + n];
            }
}

// ---------------- K2: local attention (bf16 io), register softmax ------------
__global__ __launch_bounds__(256) void attn_kernel(
    const unsigned short* __restrict__ q_ws, const unsigned short* __restrict__ k_ws,
    const unsigned short* __restrict__ v_ws,
    const float* __restrict__ rel_h, const float* __restrict__ rel_w,
    unsigned short* __restrict__ ao_ws)
{
    __shared__ float kwin[WPX * KSTR];   // holds k, then v
    __shared__ float relT[5 * KSTR];

    int t = threadIdx.x;
    int tile = blockIdx.x;
    int n = blockIdx.y;
    int b = blockIdx.z;
    int tr = tile / 7, tc = tile - tr * 7;
    int h0 = tr * TH, w0 = tc * TW;
    const float* rel = (n == 0) ? rel_h : rel_w;
    const size_t base = (size_t)b * HW * CC + n * HD;

    {
        int c8 = t & 15, pw0 = t >> 4;
#pragma unroll
        for (int it = 0; it < 6; it++) {
            int pw = pw0 + it * 16;
            int wr = pw / 12, wc = pw - wr * 12;
            int gh = h0 + wr - 2, gw = w0 + wc - 2;
            float f[8] = {0.f, 0.f, 0.f, 0.f, 0.f, 0.f, 0.f, 0.f};
            if (gh >= 0 && gh < HH && gw >= 0 && gw < WW) {
                uint4 u = *(const uint4*)(k_ws + base + (size_t)(gh * WW + gw) * CC + c8 * 8);
                f[0] = bflo(u.x); f[1] = bfhi(u.x); f[2] = bflo(u.y); f[3] = bfhi(u.y);
                f[4] = bflo(u.z); f[5] = bfhi(u.z); f[6] = bflo(u.w); f[7] = bfhi(u.w);
            }
            *(float4*)&kwin[pw * KSTR + c8 * 8]     = make_float4(f[0], f[1], f[2], f[3]);
            *(float4*)&kwin[pw * KSTR + c8 * 8 + 4] = make_float4(f[4], f[5], f[6], f[7]);
        }
        if (t < 128) {
#pragma unroll
            for (int tt = 0; tt < 5; tt++)
                relT[tt * KSTR + t] = rel[t * 5 + tt];
        }
    }
    __syncthreads();

    int px = t >> 3, c4g = t & 7;
    int pr = px >> 3, pc = px & 7;
    int ghp = h0 + pr, gwp = w0 + pc;
    const size_t pbase = base + (size_t)(ghp * WW + gwp) * CC;

    float4 q4[4];
#pragma unroll
    for (int i = 0; i < 4; i++) {
        uint2 uq = *(const uint2*)(q_ws + pbase + (c4g + 8 * i) * 4);
        q4[i] = make_float4(bflo(uq.x), bfhi(uq.x), bflo(uq.y), bfhi(uq.y));
    }

    float acc[30];
#pragma unroll
    for (int tt = 0; tt < 30; tt++) acc[tt] = 0.f;
#pragma unroll
    for (int i = 0; i < 4; i++) {
        float4 q = q4[i];
        int co = (c4g + 8 * i) * 4;
#pragma unroll
        for (int tt = 0; tt < 25; tt++) {
            int di = tt / 5, dj = tt - 5 * (tt / 5);
            int wpx = (pr + di) * WC + pc + dj;
            float4 k4 = *(const float4*)&kwin[wpx * KSTR + co];
            acc[tt] += q.x * k4.x + q.y * k4.y + q.z * k4.z + q.w * k4.w;
        }
#pragma unroll
        for (int tt = 0; tt < 5; tt++) {
            float4 r4 = *(const float4*)&relT[tt * KSTR + co];
            acc[25 + tt] += q.x * r4.x + q.y * r4.y + q.z * r4.z + q.w * r4.w;
        }
    }
#pragma unroll
    for (int tt = 0; tt < 30; tt++) {
#pragma unroll
        for (int m = 1; m < 8; m <<= 1)
            acc[tt] += __shfl_xor(acc[tt], m, 64);
    }
    // register softmax (all 8 lanes of a pixel hold identical sums)
    {
        const float inv = 0.08838834764831845f;
        float mx = -1e30f;
#pragma unroll
        for (int tt = 0; tt < 25; tt++) {
            int di = tt / 5, dj = tt - 5 * (tt / 5);
            acc[tt] = (acc[tt] + ((n == 0) ? acc[25 + di] : acc[25 + dj])) * inv;
            mx = fmaxf(mx, acc[tt]);
        }
        float sum = 0.f;
#pragma unroll
        for (int tt = 0; tt < 25; tt++) { acc[tt] = __expf(acc[tt] - mx); sum += acc[tt]; }
        float rs = 1.f / sum;
#pragma unroll
        for (int tt = 0; tt < 25; tt++) acc[tt] *= rs;
    }
    __syncthreads();   // all k reads done

    {   // stage v into same buffer
        int c8 = t & 15, pw0 = t >> 4;
#pragma unroll
        for (int it = 0; it < 6; it++) {
            int pw = pw0 + it * 16;
            int wr = pw / 12, wc = pw - wr * 12;
            int gh = h0 + wr - 2, gw = w0 + wc - 2;
            float f[8] = {0.f, 0.f, 0.f, 0.f, 0.f, 0.f, 0.f, 0.f};
            if (gh >= 0 && gh < HH && gw >= 0 && gw < WW) {
                uint4 u = *(const uint4*)(v_ws + base + (size_t)(gh * WW + gw) * CC + c8 * 8);
                f[0] = bflo(u.x); f[1] = bfhi(u.x); f[2] = bflo(u.y); f[3] = bfhi(u.y);
                f[4] = bflo(u.z); f[5] = bfhi(u.z); f[6] = bflo(u.w); f[7] = bfhi(u.w);
            }
            *(float4*)&kwin[pw * KSTR + c8 * 8]     = make_float4(f[0], f[1], f[2], f[3]);
            *(float4*)&kwin[pw * KSTR + c8 * 8 + 4] = make_float4(f[4], f[5], f[6], f[7]);
        }
    }
    __syncthreads();

    float4 oacc[4];
#pragma unroll
    for (int i = 0; i < 4; i++) oacc[i] = make_float4(0.f, 0.f, 0.f, 0.f);
#pragma unroll
    for (int tt = 0; tt < 25; tt++) {
        int di = tt / 5, dj = tt - 5 * (tt / 5);
        int wpx = (pr + di) * WC + pc + dj;
        float a = acc[tt];
#pragma unroll
        for (int i = 0; i < 4; i++) {
            float4 v4 = *(const float4*)&kwin[wpx * KSTR + (c4g + 8 * i) * 4];
            oacc[i].x += a * v4.x; oacc[i].y += a * v4.y;
            oacc[i].z += a * v4.z; oacc[i].w += a * v4.w;
        }
    }
#pragma unroll
    for (int i = 0; i < 4; i++) {
        uint2 pk;
        pk.x = (unsigned int)f2bf(oacc[i].x) | ((unsigned int)f2bf(oacc[i].y) << 16);
        pk.y = (unsigned int)f2bf(oacc[i].z) | ((unsigned int)f2bf(oacc[i].w) << 16);
        *(uint2*)(ao_ws + pbase + (c4g + 8 * i) * 4) = pk;
    }
}

// ---------------- K4: SE squeeze via MFMA + fused channel-mean ---------------
// grid 196 blocks x 256 thr; wave handles one 16-px M-tile (784 tiles)
__global__ __launch_bounds__(256) void se_in_mfma(
    const float* __restrict__ y2, const unsigned short* __restrict__ wse,
    const float* __restrict__ gin, const float* __restrict__ bin,
    const float* __restrict__ min_, const float* __restrict__ vin,
    float* __restrict__ s_ws, float* __restrict__ psum)
{
    int wave = threadIdx.x >> 6, lane = threadIdx.x & 63;
    int tile = blockIdx.x * 4 + wave;      // 0..783
    int gp0 = tile * 16;
    int b = tile / 196;                    // 196 tiles per batch
    int lm = lane & 15, lq = lane >> 4;

    f32x4 acc = (f32x4){0.f, 0.f, 0.f, 0.f};
    const float* ya = y2 + (size_t)(gp0 + lm) * CC;
#pragma unroll
    for (int k0 = 0; k0 < 256; k0 += 32) {
        int kb = k0 + lq * 8;
        float4 f0 = *(const float4*)(ya + kb);
        float4 f1 = *(const float4*)(ya + kb + 4);
        unsigned short pk[8] = {f2bf(f0.x), f2bf(f0.y), f2bf(f0.z), f2bf(f0.w),
                                f2bf(f1.x), f2bf(f1.y), f2bf(f1.z), f2bf(f1.w)};
        bf16x8 af = *(bf16x8*)pk;
        bf16x8 bf = *(const bf16x8*)(wse + (size_t)lm * CC + kb);
        acc = __builtin_amdgcn_mfma_f32_16x16x32_bf16(af, bf, acc, 0, 0, 0);
    }
    float sc = gin[lm] * rsqrtf(vin[lm] + 1e-5f);
    float off = bin[lm] - min_[lm] * sc;
    float sum4 = 0.f;
#pragma unroll
    for (int r = 0; r < 4; r++) {
        int row = lq * 4 + r;
        float v = fmaxf(acc[r] * sc + off, 0.f);
        s_ws[(size_t)(gp0 + row) * 16 + lm] = v;
        sum4 += v;
    }
    sum4 += __shfl_xor(sum4, 16, 64);
    sum4 += __shfl_xor(sum4, 32, 64);
    if (lane < 16) atomicAdd(&psum[b * 16 + lane], sum4);
}

// ---------------- K5: SE gate + excite conv + BN + fp32 store (NCHW) ---------
// grid (98, 4): 32 px per block, all 256 output channels
__global__ __launch_bounds__(256) void se_out_kernel(
    const float* __restrict__ s_ws, const float* __restrict__ psum,
    const float* __restrict__ fc1, const float* __restrict__ fc2,
    const float* __restrict__ se_Wout,
    const float* __restrict__ gout, const float* __restrict__ bout,
    const float* __restrict__ mout, const float* __restrict__ vout,
    float* __restrict__ out)
{
    int b = blockIdx.y;
    int px0 = blockIdx.x * 32;
    __shared__ float sl[32 * 17];
    __shared__ float wg[256 * 20];
    __shared__ float bo[256];
    __shared__ float gg[16];
    int t = threadIdx.x;

    if (t < 16) {   // gate, redundant per block
        float h = 0.f;
#pragma unroll
        for (int jj = 0; jj < 16; jj++)
            h += (psum[b * 16 + jj] * (1.f / 3136.f)) * fc1[jj];
        h = fmaxf(h, 0.f);
        float z = h * fc2[t];
        gg[t] = 1.f / (1.f + __expf(-z));
    }
    {
        const float* sb = s_ws + (size_t)(b * HW + px0) * 16;
#pragma unroll
        for (int i = 0; i < 2; i++) {
            int idx = t + 256 * i;
            sl[(idx >> 4) * 17 + (idx & 15)] = sb[idx];
        }
    }
    __syncthreads();
    {   // fold weights: wg[o][k] = Wout[o][k] * g[k] * sc2[o]
        float sc = gout[t] * rsqrtf(vout[t] + 1e-5f);
        bo[t] = bout[t] - mout[t] * sc;
        const float* wr = se_Wout + (size_t)t * 16;
#pragma unroll
        for (int k = 0; k < 16; k++)
            wg[t * 20 + k] = wr[k] * gg[k] * sc;
    }
    __syncthreads();

    int px = t & 31, og = t >> 5;          // 8 groups x 32 o
    float4 s0 = *(float4*)&sl[px * 17 + 0];
    float4 s1v = *(float4*)&sl[px * 17 + 4];
    float4 s2v = *(float4*)&sl[px * 17 + 8];
    float4 s3 = *(float4*)&sl[px * 17 + 12];
    float* ob = out + (size_t)b * CC * HW + px0 + px;
#pragma unroll
    for (int oi = 0; oi < 32; oi++) {
        int o = og * 32 + oi;
        float4 w0 = *(float4*)&wg[o * 20 + 0];
        float4 w1 = *(float4*)&wg[o * 20 + 4];
        float4 w2 = *(float4*)&wg[o * 20 + 8];
        float4 w3 = *(float4*)&wg[o * 20 + 12];
        float r = bo[o]
            + s0.x * w0.x + s0.y * w0.y + s0.z * w0.z + s0.w * w0.w
            + s1v.x * w1.x + s1v.y * w1.y + s1v.z * w1.z + s1v.w * w1.w
            + s2v.x * w2.x + s2v.y * w2.y + s2v.z * w2.z + s2v.w * w2.w
            + s3.x * w3.x + s3.y * w3.y + s3.z * w3.z + s3.w * w3.w;
        ob[(size_t)o * HW] = r;
    }
}

extern "C" void kernel_launch(void* const* d_in, const int* in_sizes, int n_in,
                              void* d_out, int out_size, void* d_ws, size_t ws_size,
                              hipStream_t stream) {
    const float* x     = (const float*)d_in[0];
    const float* Wq    = (const float*)d_in[1];
    const float* Wk    = (const float*)d_in[2];
    const float* Wv    = (const float*)d_in[3];
    const float* rel_h = (const float*)d_in[4];
    const float* rel_w = (const float*)d_in[5];
    const float* agg_g1 = (const float*)d_in[6];
    const float* agg_b1 = (const float*)d_in[7];
    const float* agg_m1 = (const float*)d_in[8];
    const float* agg_v1 = (const float*)d_in[9];
    const float* agg_W  = (const float*)d_in[10];
    const float* agg_g2 = (const float*)d_in[11];
    const float* agg_b2 = (const float*)d_in[12];
    const float* agg_m2 = (const float*)d_in[13];
    const float* agg_v2 = (const float*)d_in[14];
    const float* se_Win = (const float*)d_in[15];
    const float* se_g_in = (const float*)d_in[16];
    const float* se_b_in = (const float*)d_in[17];
    const float* se_m_in = (const float*)d_in[18];
    const float* se_v_in = (const float*)d_in[19];
    const float* se_fc1  = (const float*)d_in[20];
    const float* se_fc2  = (const float*)d_in[21];
    const float* se_Wout = (const float*)d_in[22];
    const float* se_g_out = (const float*)d_in[23];
    const float* se_b_out = (const float*)d_in[24];
    const float* se_m_out = (const float*)d_in[25];
    const float* se_v_out = (const float*)d_in[26];

    const size_t NQ = (size_t)BB * HW * CC;   // 3,211,264
    unsigned short* q_ws  = (unsigned short*)d_ws;   // bf16, NQ each
    unsigned short* k_ws  = q_ws + NQ;
    unsigned short* v_ws  = k_ws + NQ;
    unsigned short* ao_ws = v_ws + NQ;
    unsigned short* xt    = ao_ws;                   // alias: xt dead before ao born
    float* y2_ws = (float*)d_ws;                     // alias over q+k (4*NQ bytes)
    float* s_ws  = (float*)(ao_ws + NQ);
    float* psum  = s_ws + (size_t)BB * HW * 16;
    unsigned short* wbf = (unsigned short*)(psum + 64);  // 4x65536 + 4096 bf16

    xt_cvt<<<dim3(49, 4, 4), 256, 0, stream>>>(x, xt);
    wcvt<<<dim3(64, 5), 256, 0, stream>>>(Wq, Wk, Wv, agg_W, se_Win, wbf, psum);
    qkv_mfma<<<dim3(98, 2, 3), 256, 0, stream>>>(xt, wbf, q_ws, k_ws, v_ws);
    attn_kernel<<<dim3(98, 2, 4), 256, 0, stream>>>(q_ws, k_ws, v_ws, rel_h, rel_w, ao_ws);
    agg_mfma<<<dim3(98, 2), 256, 0, stream>>>(ao_ws, wbf + 3 * 65536,
        agg_g1, agg_b1, agg_m1, agg_v1, agg_g2, agg_b2, agg_m2, agg_v2, y2_ws);
    se_in_mfma<<<dim3(196), 256, 0, stream>>>(y2_ws, wbf + 4 * 65536,
        se_g_in, se_b_in, se_m_in, se_v_in, s_ws, psum);
    se_out_kernel<<<dim3(98, 4), 256, 0, stream>>>(s_ws, psum, se_fc1, se_fc2,
        se_Wout, se_g_out, se_b_out, se_m_out, se_v_out, (float*)d_out);
}